// Round 1
// baseline (569.865 us; speedup 1.0000x reference)
//
#include <hip/hip_runtime.h>
#include <cstdint>
#include <cstddef>

// Problem constants
#define TT   2048   // tokens
#define DM   4096   // d_model
#define NH   32     // q heads
#define NG   8      // kv groups
#define HD   128    // head dim
#define QKVN 6144   // (32+16)*128
#define KOFF 4096   // k column offset in qkv
#define VOFF 5120   // v column offset in qkv

typedef __attribute__((ext_vector_type(8))) short bf16x8;   // 8 bf16 (4 VGPRs)
typedef __attribute__((ext_vector_type(4))) float f32x4;    // MFMA 16x16 accumulator
typedef unsigned short u16;

__device__ __forceinline__ u16 f2b(float f) {   // f32 -> bf16 RNE
  unsigned u = __builtin_bit_cast(unsigned, f);
  u += 0x7fffu + ((u >> 16) & 1u);
  return (u16)(u >> 16);
}
__device__ __forceinline__ float b2f(u16 s) {
  unsigned u = ((unsigned)s) << 16;
  return __builtin_bit_cast(float, u);
}

// async global->LDS, 16B per lane; LDS dest = wave-uniform base + lane*16
__device__ __forceinline__ void gload_lds16(const void* g, void* l) {
  __builtin_amdgcn_global_load_lds(
      (const __attribute__((address_space(1))) unsigned int*)g,
      (__attribute__((address_space(3))) unsigned int*)l,
      16, 0, 0);
}

// ---------------- elementwise f32 -> bf16 ----------------
__global__ __launch_bounds__(256) void cvt_f32_bf16(
    const float* __restrict__ src, u16* __restrict__ dst, int n) {
  for (int i = (blockIdx.x * 256 + threadIdx.x) * 4; i < n; i += gridDim.x * 256 * 4) {
    float4 v = *(const float4*)(src + i);
    ushort4 o;
    o.x = f2b(v.x); o.y = f2b(v.y); o.z = f2b(v.z); o.w = f2b(v.w);
    *(ushort4*)(dst + i) = o;
  }
}

// ---------------- transpose + convert: src f32 [R][C] -> dst bf16 [C][R] ----------------
__global__ __launch_bounds__(256) void transpose_cvt(
    const float* __restrict__ src, u16* __restrict__ dst, int R, int C) {
  __shared__ u16 tile[64][66];
  const int rb = blockIdx.y * 64, cb = blockIdx.x * 64;
  const int tid = threadIdx.x;
#pragma unroll
  for (int it = 0; it < 16; ++it) {
    int idx = it * 256 + tid;
    int i = idx >> 6, j = idx & 63;
    tile[i][j] = f2b(src[(size_t)(rb + i) * C + cb + j]);
  }
  __syncthreads();
#pragma unroll
  for (int it = 0; it < 16; ++it) {
    int idx = it * 256 + tid;
    int j = idx >> 6, i = idx & 63;
    dst[(size_t)(cb + j) * R + rb + i] = tile[i][j];
  }
}

// ---------------- bf16 GEMM: C[M][N] = A[M][K] * Bt[N][K]^T ----------------
// 128x128 tile, BK=64, 4 waves (2x2 of 64x64), m97-style global_load_lds prefetch
template <bool OUT_BF16>
__global__ __launch_bounds__(256) void gemm_bt(
    const u16* __restrict__ A, const u16* __restrict__ Bt, void* __restrict__ Cout,
    int M, int N, int K) {
  __shared__ __align__(16) u16 sA[2][128 * 64];
  __shared__ __align__(16) u16 sB[2][128 * 64];
  const int tid = threadIdx.x;
  const int wid = tid >> 6, lane = tid & 63;
  const int lane15 = lane & 15, laneh = lane >> 4;
  const int m0 = blockIdx.y * 128, n0 = blockIdx.x * 128;
  const int wr = wid >> 1, wc = wid & 1;

  f32x4 acc[4][4];
#pragma unroll
  for (int m = 0; m < 4; ++m)
#pragma unroll
    for (int n = 0; n < 4; ++n)
#pragma unroll
      for (int r = 0; r < 4; ++r) acc[m][n][r] = 0.f;

  auto stage = [&](int buf, int t) {
    const int k0 = t * 64;
#pragma unroll
    for (int i = 0; i < 4; ++i) {
      const int ebase = (wid * 4 + i) * 512;         // wave-uniform LDS elem base
      const int e = ebase + lane * 8;
      const int row = e >> 6, col = e & 63;
      gload_lds16(A + (size_t)(m0 + row) * K + k0 + col, &sA[buf][ebase]);
      gload_lds16(Bt + (size_t)(n0 + row) * K + k0 + col, &sB[buf][ebase]);
    }
  };

  const int NT = K >> 6;
  stage(0, 0);
  __syncthreads();
  for (int t = 0; t < NT; ++t) {
    const int cur = t & 1;
    if (t + 1 < NT) stage(cur ^ 1, t + 1);
#pragma unroll
    for (int ks = 0; ks < 2; ++ks) {
      bf16x8 af[4], bfr[4];
#pragma unroll
      for (int m = 0; m < 4; ++m)
        af[m] = *(const bf16x8*)&sA[cur][(wr * 64 + m * 16 + lane15) * 64 + ks * 32 + laneh * 8];
#pragma unroll
      for (int n = 0; n < 4; ++n)
        bfr[n] = *(const bf16x8*)&sB[cur][(wc * 64 + n * 16 + lane15) * 64 + ks * 32 + laneh * 8];
#pragma unroll
      for (int m = 0; m < 4; ++m)
#pragma unroll
        for (int n = 0; n < 4; ++n)
          acc[m][n] = __builtin_amdgcn_mfma_f32_16x16x32_bf16(af[m], bfr[n], acc[m][n], 0, 0, 0);
    }
    __syncthreads();
  }
  // epilogue: D row = (lane>>4)*4+r, col = lane&15 (m89-verified layout)
#pragma unroll
  for (int m = 0; m < 4; ++m)
#pragma unroll
    for (int n = 0; n < 4; ++n)
#pragma unroll
      for (int r = 0; r < 4; ++r) {
        const int row = m0 + wr * 64 + m * 16 + laneh * 4 + r;
        const int col = n0 + wc * 64 + n * 16 + lane15;
        const float v = acc[m][n][r];
        if (OUT_BF16) ((u16*)Cout)[(size_t)row * N + col] = f2b(v);
        else          ((float*)Cout)[(size_t)row * N + col] = v;
      }
}

// ---------------- RoPE + rearrange: qkv -> Qr[h][t][d], Kr[g][t][d] ----------------
__global__ __launch_bounds__(256) void rope_rearrange(
    const u16* __restrict__ qkv, const float* __restrict__ cosT,
    const float* __restrict__ sinT, u16* __restrict__ Qr, u16* __restrict__ Kr) {
  const int u = blockIdx.x * 4 + (threadIdx.x >> 6);  // u = e*TT + t, e in [0,40)
  const int lane = threadIdx.x & 63;
  const int t = u & (TT - 1);
  const int e = u >> 11;
  const u16* in;
  u16* outp;
  if (e < NH) {
    in = qkv + (size_t)t * QKVN + e * HD;
    outp = Qr + ((size_t)e * TT + t) * HD;
  } else {
    const int g = e - NH;
    in = qkv + (size_t)t * QKVN + KOFF + g * HD;
    outp = Kr + ((size_t)g * TT + t) * HD;
  }
  const float u1 = b2f(in[lane]), u2 = b2f(in[lane + 64]);
  const float c1 = cosT[t * HD + lane], s1 = sinT[t * HD + lane];
  const float c2 = cosT[t * HD + lane + 64], s2 = sinT[t * HD + lane + 64];
  outp[lane]      = f2b(u1 * c1 - u2 * s1);   // d<64:  u*cos - u[d+64]*sin
  outp[lane + 64] = f2b(u2 * c2 + u1 * s2);   // d>=64: u*cos + u[d-64]*sin
}

// ---------------- V transpose per group: qkv V block -> VT[g][d][t] ----------------
__global__ __launch_bounds__(256) void vtrans(
    const u16* __restrict__ qkv, u16* __restrict__ VT) {
  __shared__ u16 tile[64][66];
  const int g = blockIdx.z;
  const int t0 = blockIdx.x * 64, d0 = blockIdx.y * 64;
  const int tid = threadIdx.x;
#pragma unroll
  for (int it = 0; it < 16; ++it) {
    int idx = it * 256 + tid;
    int i = idx >> 6, j = idx & 63;                       // i: t, j: d
    tile[i][j] = qkv[(size_t)(t0 + i) * QKVN + VOFF + g * HD + d0 + j];
  }
  __syncthreads();
#pragma unroll
  for (int it = 0; it < 16; ++it) {
    int idx = it * 256 + tid;
    int j = idx >> 6, i = idx & 63;
    VT[((size_t)g * HD + d0 + j) * TT + t0 + i] = tile[i][j];
  }
}

// ---------------- causal flash attention (GQA) ----------------
// block = (head h, q-tile qt): 128 q rows; 4 waves x 32 rows; KV tiles of 128
__global__ __launch_bounds__(256) void attn(
    const u16* __restrict__ Qr, const u16* __restrict__ Kr,
    const u16* __restrict__ VT, u16* __restrict__ AO) {
  __shared__ __align__(16) u16 sK[128 * 128];      // [s][d]
  __shared__ __align__(16) u16 sV[128 * 128];      // [d][s]  (VT tile)
  __shared__ __align__(16) u16 sP[4][32 * 128];    // per-wave P slab [row][s]
  const int h = blockIdx.x >> 4, qt = blockIdx.x & 15;
  const int g = h >> 2;
  const int tid = threadIdx.x, wid = tid >> 6, lane = tid & 63;
  const int lane15 = lane & 15, laneh = lane >> 4;
  const u16* Qh = Qr + (size_t)h * TT * HD;
  const u16* Kg = Kr + (size_t)g * TT * HD;
  const u16* Vg = VT + (size_t)g * HD * TT;

  // Q fragments held in registers: a[j] = Q[row=lane&15][k=(lane>>4)*8+j]
  bf16x8 qf[2][4];
  const int qrow0 = qt * 128 + wid * 32;
#pragma unroll
  for (int m = 0; m < 2; ++m)
#pragma unroll
    for (int ks = 0; ks < 4; ++ks)
      qf[m][ks] = *(const bf16x8*)(Qh + (size_t)(qrow0 + m * 16 + lane15) * HD + ks * 32 + laneh * 8);

  f32x4 acc_o[2][8];
  float mrow[2][4], lrow[2][4];
#pragma unroll
  for (int m = 0; m < 2; ++m) {
#pragma unroll
    for (int n = 0; n < 8; ++n)
#pragma unroll
      for (int r = 0; r < 4; ++r) acc_o[m][n][r] = 0.f;
#pragma unroll
    for (int r = 0; r < 4; ++r) { mrow[m][r] = -1e30f; lrow[m][r] = 0.f; }
  }
  const float scale = 0.08838834764831845f;  // 1/sqrt(128)

  for (int kv = 0; kv <= qt; ++kv) {
    // stage K tile (contiguous 32KB) and VT tile (row stride TT)
#pragma unroll
    for (int i = 0; i < 8; ++i) {
      const int ebase = (wid * 8 + i) * 512;
      gload_lds16(Kg + (size_t)kv * (128 * HD) + ebase + lane * 8, &sK[ebase]);
    }
#pragma unroll
    for (int i = 0; i < 8; ++i) {
      const int ebase = (wid * 8 + i) * 512;
      const int e2 = ebase + lane * 8;
      const int d = e2 >> 7, c = e2 & 127;
      gload_lds16(Vg + (size_t)d * TT + kv * 128 + c, &sV[ebase]);
    }
    __syncthreads();

    // S = Q K^T
    f32x4 s[2][8];
#pragma unroll
    for (int m = 0; m < 2; ++m)
#pragma unroll
      for (int n = 0; n < 8; ++n)
#pragma unroll
        for (int r = 0; r < 4; ++r) s[m][n][r] = 0.f;
#pragma unroll
    for (int ks = 0; ks < 4; ++ks) {
      bf16x8 kf[8];
#pragma unroll
      for (int n = 0; n < 8; ++n)
        kf[n] = *(const bf16x8*)&sK[(n * 16 + lane15) * 128 + ks * 32 + laneh * 8];
#pragma unroll
      for (int m = 0; m < 2; ++m)
#pragma unroll
        for (int n = 0; n < 8; ++n)
          s[m][n] = __builtin_amdgcn_mfma_f32_16x16x32_bf16(qf[m][ks], kf[n], s[m][n], 0, 0, 0);
    }
    // scale + causal mask (only diagonal tile needs the mask)
    if (kv == qt) {
#pragma unroll
      for (int m = 0; m < 2; ++m)
#pragma unroll
        for (int n = 0; n < 8; ++n)
#pragma unroll
          for (int r = 0; r < 4; ++r) {
            const int ql = wid * 32 + m * 16 + laneh * 4 + r;
            const int sl = n * 16 + lane15;
            s[m][n][r] = (sl > ql) ? -1e30f : s[m][n][r] * scale;
          }
    } else {
#pragma unroll
      for (int m = 0; m < 2; ++m)
#pragma unroll
        for (int n = 0; n < 8; ++n)
#pragma unroll
          for (int r = 0; r < 4; ++r) s[m][n][r] *= scale;
    }
    // online softmax: row lives in 16 lanes sharing (lane>>4); reduce via shfl_xor 1/2/4/8
#pragma unroll
    for (int m = 0; m < 2; ++m)
#pragma unroll
      for (int r = 0; r < 4; ++r) {
        float pm = s[m][0][r];
#pragma unroll
        for (int n = 1; n < 8; ++n) pm = fmaxf(pm, s[m][n][r]);
        pm = fmaxf(pm, __shfl_xor(pm, 1));
        pm = fmaxf(pm, __shfl_xor(pm, 2));
        pm = fmaxf(pm, __shfl_xor(pm, 4));
        pm = fmaxf(pm, __shfl_xor(pm, 8));
        const float mnew = fmaxf(mrow[m][r], pm);
        const float corr = __expf(mrow[m][r] - mnew);
        mrow[m][r] = mnew;
        float ps = 0.f;
#pragma unroll
        for (int n = 0; n < 8; ++n) {
          const float p = __expf(s[m][n][r] - mnew);
          s[m][n][r] = p;
          ps += p;
        }
        ps += __shfl_xor(ps, 1); ps += __shfl_xor(ps, 2);
        ps += __shfl_xor(ps, 4); ps += __shfl_xor(ps, 8);
        lrow[m][r] = lrow[m][r] * corr + ps;
#pragma unroll
        for (int n = 0; n < 8; ++n) acc_o[m][n][r] *= corr;
      }
    // P (D-frag layout) -> per-wave LDS slab -> re-read in A-frag layout
#pragma unroll
    for (int m = 0; m < 2; ++m)
#pragma unroll
      for (int n = 0; n < 8; ++n)
#pragma unroll
        for (int r = 0; r < 4; ++r)
          sP[wid][(m * 16 + laneh * 4 + r) * 128 + n * 16 + lane15] = f2b(s[m][n][r]);
    // PV: O += P @ V
#pragma unroll
    for (int ks = 0; ks < 4; ++ks) {
      bf16x8 pf[2], vf[8];
#pragma unroll
      for (int m = 0; m < 2; ++m)
        pf[m] = *(const bf16x8*)&sP[wid][(m * 16 + lane15) * 128 + ks * 32 + laneh * 8];
#pragma unroll
      for (int n = 0; n < 8; ++n)
        vf[n] = *(const bf16x8*)&sV[(n * 16 + lane15) * 128 + ks * 32 + laneh * 8];
#pragma unroll
      for (int m = 0; m < 2; ++m)
#pragma unroll
        for (int n = 0; n < 8; ++n)
          acc_o[m][n] = __builtin_amdgcn_mfma_f32_16x16x32_bf16(pf[m], vf[n], acc_o[m][n], 0, 0, 0);
    }
    __syncthreads();  // all waves done with sK/sV before next stage overwrites
  }
  // epilogue: AO[t][h*128+d] = O / l
#pragma unroll
  for (int m = 0; m < 2; ++m) {
    float inv[4];
#pragma unroll
    for (int r = 0; r < 4; ++r) inv[r] = 1.f / lrow[m][r];
#pragma unroll
    for (int n = 0; n < 8; ++n)
#pragma unroll
      for (int r = 0; r < 4; ++r) {
        const int trow = qt * 128 + wid * 32 + m * 16 + laneh * 4 + r;
        AO[(size_t)trow * DM + h * HD + n * 16 + lane15] = f2b(acc_o[m][n][r] * inv[r]);
      }
  }
}

// ---------------- launch ----------------
extern "C" void kernel_launch(void* const* d_in, const int* in_sizes, int n_in,
                              void* d_out, int out_size, void* d_ws, size_t ws_size,
                              hipStream_t stream) {
  const float* x     = (const float*)d_in[0];
  const float* w_qkv = (const float*)d_in[1];
  const float* w_out = (const float*)d_in[2];
  const float* cosT  = (const float*)d_in[3];
  const float* sinT  = (const float*)d_in[4];
  // d_in[5] (mask) unused: causal mask computed analytically
  float* out = (float*)d_out;

  char* ws = (char*)d_ws;
  // layout (bytes): wT region reused for wqT then woT (stream-ordered)
  u16* wT  = (u16*)(ws);                                   // 6144*4096 bf16 = 50331648 B
  u16* xb  = (u16*)(ws + 50331648);                        // 2048*4096 bf16 = 16777216 B (reused as AO)
  u16* qkv = (u16*)(ws + 50331648 + 16777216);             // 2048*6144 bf16 = 25165824 B
  u16* Qr  = (u16*)(ws + 50331648 + 16777216 + 25165824);  // 32*2048*128 bf16
  u16* Kr  = Qr + (size_t)NH * TT * HD;                    // 8*2048*128 bf16
  u16* VT  = Kr + (size_t)NG * TT * HD;                    // 8*128*2048 bf16
  u16* AO  = xb;                                           // alias: xb dead after GEMM1

  cvt_f32_bf16<<<2048, 256, 0, stream>>>(x, xb, TT * DM);
  transpose_cvt<<<dim3(QKVN / 64, DM / 64), 256, 0, stream>>>(w_qkv, wT, DM, QKVN);
  gemm_bt<true><<<dim3(QKVN / 128, TT / 128), 256, 0, stream>>>(xb, wT, qkv, TT, QKVN, DM);
  rope_rearrange<<<(TT * (NH + NG)) / 4, 256, 0, stream>>>(qkv, cosT, sinT, Qr, Kr);
  vtrans<<<dim3(TT / 64, HD / 64, NG), 256, 0, stream>>>(qkv, VT);
  transpose_cvt<<<dim3(DM / 64, DM / 64), 256, 0, stream>>>(w_out, wT, DM, DM);  // after GEMM1: safe reuse
  attn<<<NH * (TT / 128), 256, 0, stream>>>(Qr, Kr, VT, AO);
  gemm_bt<false><<<dim3(DM / 128, TT / 128), 256, 0, stream>>>(AO, wT, out, TT, DM, DM);
}

// Round 2
// 493.339 us; speedup vs baseline: 1.1551x; 1.1551x over previous
//
#include <hip/hip_runtime.h>
#include <cstdint>
#include <cstddef>

// Problem constants
#define TT   2048   // tokens
#define DM   4096   // d_model
#define NH   32     // q heads
#define NG   8      // kv groups
#define HD   128    // head dim
#define QKVN 6144   // (32+16)*128
#define KOFF 4096   // k column offset in qkv
#define VOFF 5120   // v column offset in qkv

typedef __attribute__((ext_vector_type(8))) short bf16x8;   // 8 bf16 (4 VGPRs)
typedef __attribute__((ext_vector_type(4))) float f32x4;    // MFMA 16x16 accumulator
typedef unsigned short u16;

__device__ __forceinline__ u16 f2b(float f) {   // f32 -> bf16 RNE
  unsigned u = __builtin_bit_cast(unsigned, f);
  u += 0x7fffu + ((u >> 16) & 1u);
  return (u16)(u >> 16);
}
__device__ __forceinline__ float b2f(u16 s) {
  unsigned u = ((unsigned)s) << 16;
  return __builtin_bit_cast(float, u);
}

// async global->LDS, 16B per lane; LDS dest = wave-uniform base + lane*16
__device__ __forceinline__ void gload_lds16(const void* g, void* l) {
  __builtin_amdgcn_global_load_lds(
      (const __attribute__((address_space(1))) unsigned int*)g,
      (__attribute__((address_space(3))) unsigned int*)l,
      16, 0, 0);
}

// ---------------- elementwise f32 -> bf16 ----------------
__global__ __launch_bounds__(256) void cvt_f32_bf16(
    const float* __restrict__ src, u16* __restrict__ dst, int n) {
  for (int i = (blockIdx.x * 256 + threadIdx.x) * 4; i < n; i += gridDim.x * 256 * 4) {
    float4 v = *(const float4*)(src + i);
    ushort4 o;
    o.x = f2b(v.x); o.y = f2b(v.y); o.z = f2b(v.z); o.w = f2b(v.w);
    *(ushort4*)(dst + i) = o;
  }
}

// ---------------- transpose + convert: src f32 [R][C] -> dst bf16 [C][R] ----------------
__global__ __launch_bounds__(256) void transpose_cvt(
    const float* __restrict__ src, u16* __restrict__ dst, int R, int C) {
  __shared__ u16 tile[64][66];
  const int rb = blockIdx.y * 64, cb = blockIdx.x * 64;
  const int tid = threadIdx.x;
#pragma unroll
  for (int it = 0; it < 16; ++it) {
    int idx = it * 256 + tid;
    int i = idx >> 6, j = idx & 63;
    tile[i][j] = f2b(src[(size_t)(rb + i) * C + cb + j]);
  }
  __syncthreads();
#pragma unroll
  for (int it = 0; it < 16; ++it) {
    int idx = it * 256 + tid;
    int j = idx >> 6, i = idx & 63;
    dst[(size_t)(cb + j) * R + rb + i] = tile[i][j];
  }
}

// ---------------- bf16 GEMM: C[M][N] = A[M][K] * Bt[N][K]^T ----------------
// 128x128 tile, BK=64, 4 waves (2x2 of 64x64), m97-style global_load_lds prefetch
template <bool OUT_BF16>
__global__ __launch_bounds__(256) void gemm_bt(
    const u16* __restrict__ A, const u16* __restrict__ Bt, void* __restrict__ Cout,
    int M, int N, int K) {
  __shared__ __align__(16) u16 sA[2][128 * 64];
  __shared__ __align__(16) u16 sB[2][128 * 64];
  const int tid = threadIdx.x;
  const int wid = tid >> 6, lane = tid & 63;
  const int lane15 = lane & 15, laneh = lane >> 4;
  const int m0 = blockIdx.y * 128, n0 = blockIdx.x * 128;
  const int wr = wid >> 1, wc = wid & 1;

  f32x4 acc[4][4];
#pragma unroll
  for (int m = 0; m < 4; ++m)
#pragma unroll
    for (int n = 0; n < 4; ++n)
#pragma unroll
      for (int r = 0; r < 4; ++r) acc[m][n][r] = 0.f;

  auto stage = [&](int buf, int t) {
    const int k0 = t * 64;
#pragma unroll
    for (int i = 0; i < 4; ++i) {
      const int ebase = (wid * 4 + i) * 512;         // wave-uniform LDS elem base
      const int e = ebase + lane * 8;
      const int row = e >> 6, col = e & 63;
      gload_lds16(A + (size_t)(m0 + row) * K + k0 + col, &sA[buf][ebase]);
      gload_lds16(Bt + (size_t)(n0 + row) * K + k0 + col, &sB[buf][ebase]);
    }
  };

  const int NT = K >> 6;
  stage(0, 0);
  __syncthreads();
  for (int t = 0; t < NT; ++t) {
    const int cur = t & 1;
    if (t + 1 < NT) stage(cur ^ 1, t + 1);
#pragma unroll
    for (int ks = 0; ks < 2; ++ks) {
      bf16x8 af[4], bfr[4];
#pragma unroll
      for (int m = 0; m < 4; ++m)
        af[m] = *(const bf16x8*)&sA[cur][(wr * 64 + m * 16 + lane15) * 64 + ks * 32 + laneh * 8];
#pragma unroll
      for (int n = 0; n < 4; ++n)
        bfr[n] = *(const bf16x8*)&sB[cur][(wc * 64 + n * 16 + lane15) * 64 + ks * 32 + laneh * 8];
#pragma unroll
      for (int m = 0; m < 4; ++m)
#pragma unroll
        for (int n = 0; n < 4; ++n)
          acc[m][n] = __builtin_amdgcn_mfma_f32_16x16x32_bf16(af[m], bfr[n], acc[m][n], 0, 0, 0);
    }
    __syncthreads();
  }
  // epilogue: D row = (lane>>4)*4+r, col = lane&15 (m89-verified layout)
#pragma unroll
  for (int m = 0; m < 4; ++m)
#pragma unroll
    for (int n = 0; n < 4; ++n)
#pragma unroll
      for (int r = 0; r < 4; ++r) {
        const int row = m0 + wr * 64 + m * 16 + laneh * 4 + r;
        const int col = n0 + wc * 64 + n * 16 + lane15;
        const float v = acc[m][n][r];
        if (OUT_BF16) ((u16*)Cout)[(size_t)row * N + col] = f2b(v);
        else          ((float*)Cout)[(size_t)row * N + col] = v;
      }
}

// ---------------- RoPE + rearrange: qkv -> Qr[h][t][d], Kr[g][t][d] ----------------
__global__ __launch_bounds__(256) void rope_rearrange(
    const u16* __restrict__ qkv, const float* __restrict__ cosT,
    const float* __restrict__ sinT, u16* __restrict__ Qr, u16* __restrict__ Kr) {
  const int u = blockIdx.x * 4 + (threadIdx.x >> 6);  // u = e*TT + t, e in [0,40)
  const int lane = threadIdx.x & 63;
  const int t = u & (TT - 1);
  const int e = u >> 11;
  const u16* in;
  u16* outp;
  if (e < NH) {
    in = qkv + (size_t)t * QKVN + e * HD;
    outp = Qr + ((size_t)e * TT + t) * HD;
  } else {
    const int g = e - NH;
    in = qkv + (size_t)t * QKVN + KOFF + g * HD;
    outp = Kr + ((size_t)g * TT + t) * HD;
  }
  const float u1 = b2f(in[lane]), u2 = b2f(in[lane + 64]);
  const float c1 = cosT[t * HD + lane], s1 = sinT[t * HD + lane];
  const float c2 = cosT[t * HD + lane + 64], s2 = sinT[t * HD + lane + 64];
  outp[lane]      = f2b(u1 * c1 - u2 * s1);   // d<64:  u*cos - u[d+64]*sin
  outp[lane + 64] = f2b(u2 * c2 + u1 * s2);   // d>=64: u*cos + u[d-64]*sin
}

// ---------------- V transpose per group: qkv V block -> VT[g][d][t] ----------------
__global__ __launch_bounds__(256) void vtrans(
    const u16* __restrict__ qkv, u16* __restrict__ VT) {
  __shared__ u16 tile[64][66];
  const int g = blockIdx.z;
  const int t0 = blockIdx.x * 64, d0 = blockIdx.y * 64;
  const int tid = threadIdx.x;
#pragma unroll
  for (int it = 0; it < 16; ++it) {
    int idx = it * 256 + tid;
    int i = idx >> 6, j = idx & 63;                       // i: t, j: d
    tile[i][j] = qkv[(size_t)(t0 + i) * QKVN + VOFF + g * HD + d0 + j];
  }
  __syncthreads();
#pragma unroll
  for (int it = 0; it < 16; ++it) {
    int idx = it * 256 + tid;
    int j = idx >> 6, i = idx & 63;
    VT[((size_t)g * HD + d0 + j) * TT + t0 + i] = tile[i][j];
  }
}

// ---------------- causal flash attention (GQA) ----------------
// block = (head h, q-tile qt): 128 q rows; 4 waves x 32 rows; KV tiles of 128
// LDS 64KB (P slab aliases sK after QK^T) -> 2 blocks/CU; all tiles XOR-swizzled
// (T2): staging pre-swizzles the GLOBAL source col (rule #21), reads apply the
// same involution col ^= ((row&7)<<3) [elements].
__global__ __launch_bounds__(256) void attn(
    const u16* __restrict__ Qr, const u16* __restrict__ Kr,
    const u16* __restrict__ VT, u16* __restrict__ AO) {
  __shared__ __align__(16) u16 sK[128 * 128];      // [s][d] swizzled; P slab after QK^T
  __shared__ __align__(16) u16 sV[128 * 128];      // [d][s] swizzled
  // XCD-chunked bijective swizzle: 512 blocks = 8 XCDs x 64; each XCD sees 1 KV group
  const int bid = blockIdx.x;
  const int swz = (bid & 7) * 64 + (bid >> 3);
  const int h = swz >> 4, qt = swz & 15;
  const int g = h >> 2;
  const int tid = threadIdx.x, wid = tid >> 6, lane = tid & 63;
  const int lane15 = lane & 15, laneh = lane >> 4;
  const int xorL = (lane15 & 7) << 3;              // read-side swizzle (row = *+lane15)
  const u16* Qh = Qr + (size_t)h * TT * HD;
  const u16* Kg = Kr + (size_t)g * TT * HD;
  const u16* Vg = VT + (size_t)g * HD * TT;

  // Q fragments held in registers: a[j] = Q[row=lane&15][k=(lane>>4)*8+j]
  bf16x8 qf[2][4];
  const int qrow0 = qt * 128 + wid * 32;
#pragma unroll
  for (int m = 0; m < 2; ++m)
#pragma unroll
    for (int ks = 0; ks < 4; ++ks)
      qf[m][ks] = *(const bf16x8*)(Qh + (size_t)(qrow0 + m * 16 + lane15) * HD + ks * 32 + laneh * 8);

  f32x4 acc_o[2][8];
  float mrow[2][4], lrow[2][4];
#pragma unroll
  for (int m = 0; m < 2; ++m) {
#pragma unroll
    for (int n = 0; n < 8; ++n)
#pragma unroll
      for (int r = 0; r < 4; ++r) acc_o[m][n][r] = 0.f;
#pragma unroll
    for (int r = 0; r < 4; ++r) { mrow[m][r] = -1e30f; lrow[m][r] = 0.f; }
  }
  const float scale = 0.08838834764831845f;  // 1/sqrt(128)

  for (int kv = 0; kv <= qt; ++kv) {
    // stage K tile [s][d] and VT tile [d][s]; source col pre-swizzled so that
    // linear LDS write + swizzled read = correct data (involution)
#pragma unroll
    for (int i = 0; i < 8; ++i) {
      const int ebase = (wid * 8 + i) * 512;
      const int e = ebase + lane * 8;
      const int row = e >> 7;
      const int col = (e & 127) ^ ((row & 7) << 3);
      gload_lds16(Kg + (size_t)(kv * 128 + row) * HD + col, &sK[ebase]);
      gload_lds16(Vg + (size_t)row * TT + kv * 128 + col, &sV[ebase]);
    }
    __syncthreads();

    // S = Q K^T
    f32x4 s[2][8];
#pragma unroll
    for (int m = 0; m < 2; ++m)
#pragma unroll
      for (int n = 0; n < 8; ++n)
#pragma unroll
        for (int r = 0; r < 4; ++r) s[m][n][r] = 0.f;
    __builtin_amdgcn_s_setprio(1);
#pragma unroll
    for (int ks = 0; ks < 4; ++ks) {
      bf16x8 kf[8];
#pragma unroll
      for (int n = 0; n < 8; ++n)
        kf[n] = *(const bf16x8*)&sK[(n * 16 + lane15) * 128 + ((ks * 32 + laneh * 8) ^ xorL)];
#pragma unroll
      for (int m = 0; m < 2; ++m)
#pragma unroll
        for (int n = 0; n < 8; ++n)
          s[m][n] = __builtin_amdgcn_mfma_f32_16x16x32_bf16(qf[m][ks], kf[n], s[m][n], 0, 0, 0);
    }
    __builtin_amdgcn_s_setprio(0);
    __syncthreads();   // all waves done reading sK before P overwrites it

    // scale + causal mask (only diagonal tile needs the mask)
    if (kv == qt) {
#pragma unroll
      for (int m = 0; m < 2; ++m)
#pragma unroll
        for (int n = 0; n < 8; ++n)
#pragma unroll
          for (int r = 0; r < 4; ++r) {
            const int ql = wid * 32 + m * 16 + laneh * 4 + r;
            const int sl = n * 16 + lane15;
            s[m][n][r] = (sl > ql) ? -1e30f : s[m][n][r] * scale;
          }
    } else {
#pragma unroll
      for (int m = 0; m < 2; ++m)
#pragma unroll
        for (int n = 0; n < 8; ++n)
#pragma unroll
          for (int r = 0; r < 4; ++r) s[m][n][r] *= scale;
    }
    // online softmax: row lives in 16 lanes sharing (lane>>4); reduce via shfl_xor 1/2/4/8
#pragma unroll
    for (int m = 0; m < 2; ++m)
#pragma unroll
      for (int r = 0; r < 4; ++r) {
        float pm = s[m][0][r];
#pragma unroll
        for (int n = 1; n < 8; ++n) pm = fmaxf(pm, s[m][n][r]);
        pm = fmaxf(pm, __shfl_xor(pm, 1));
        pm = fmaxf(pm, __shfl_xor(pm, 2));
        pm = fmaxf(pm, __shfl_xor(pm, 4));
        pm = fmaxf(pm, __shfl_xor(pm, 8));
        const float mnew = fmaxf(mrow[m][r], pm);
        const float corr = __expf(mrow[m][r] - mnew);
        mrow[m][r] = mnew;
        float ps = 0.f;
#pragma unroll
        for (int n = 0; n < 8; ++n) {
          const float p = __expf(s[m][n][r] - mnew);
          s[m][n][r] = p;
          ps += p;
        }
        ps += __shfl_xor(ps, 1); ps += __shfl_xor(ps, 2);
        ps += __shfl_xor(ps, 4); ps += __shfl_xor(ps, 8);
        lrow[m][r] = lrow[m][r] * corr + ps;
#pragma unroll
        for (int n = 0; n < 8; ++n) acc_o[m][n][r] *= corr;
      }
    // P (D-frag layout) -> per-wave 32-row slab aliased into sK (swizzled write)
#pragma unroll
    for (int m = 0; m < 2; ++m)
#pragma unroll
      for (int n = 0; n < 8; ++n)
#pragma unroll
        for (int r = 0; r < 4; ++r) {
          const int prow = wid * 32 + m * 16 + laneh * 4 + r;
          const int pcol = (n * 16 + lane15) ^ (((laneh * 4 + r) & 7) << 3);
          sK[prow * 128 + pcol] = f2b(s[m][n][r]);
        }
    // PV: O += P @ V   (pf from own slab; vf from sV; both swizzled reads)
    __builtin_amdgcn_s_setprio(1);
#pragma unroll
    for (int ks = 0; ks < 4; ++ks) {
      bf16x8 pf[2], vf[8];
#pragma unroll
      for (int m = 0; m < 2; ++m)
        pf[m] = *(const bf16x8*)&sK[(wid * 32 + m * 16 + lane15) * 128 + ((ks * 32 + laneh * 8) ^ xorL)];
#pragma unroll
      for (int n = 0; n < 8; ++n)
        vf[n] = *(const bf16x8*)&sV[(n * 16 + lane15) * 128 + ((ks * 32 + laneh * 8) ^ xorL)];
#pragma unroll
      for (int m = 0; m < 2; ++m)
#pragma unroll
        for (int n = 0; n < 8; ++n)
          acc_o[m][n] = __builtin_amdgcn_mfma_f32_16x16x32_bf16(pf[m], vf[n], acc_o[m][n], 0, 0, 0);
    }
    __builtin_amdgcn_s_setprio(0);
    __syncthreads();  // all waves done with sK(P)/sV before next stage overwrites
  }
  // epilogue: AO[t][h*128+d] = O / l
#pragma unroll
  for (int m = 0; m < 2; ++m) {
    float inv[4];
#pragma unroll
    for (int r = 0; r < 4; ++r) inv[r] = 1.f / lrow[m][r];
#pragma unroll
    for (int n = 0; n < 8; ++n)
#pragma unroll
      for (int r = 0; r < 4; ++r) {
        const int trow = qt * 128 + wid * 32 + m * 16 + laneh * 4 + r;
        AO[(size_t)trow * DM + h * HD + n * 16 + lane15] = f2b(acc_o[m][n][r] * inv[r]);
      }
  }
}

// ---------------- launch ----------------
extern "C" void kernel_launch(void* const* d_in, const int* in_sizes, int n_in,
                              void* d_out, int out_size, void* d_ws, size_t ws_size,
                              hipStream_t stream) {
  const float* x     = (const float*)d_in[0];
  const float* w_qkv = (const float*)d_in[1];
  const float* w_out = (const float*)d_in[2];
  const float* cosT  = (const float*)d_in[3];
  const float* sinT  = (const float*)d_in[4];
  // d_in[5] (mask) unused: causal mask computed analytically
  float* out = (float*)d_out;

  char* ws = (char*)d_ws;
  // layout (bytes): wT region reused for wqT then woT (stream-ordered)
  u16* wT  = (u16*)(ws);                                   // 6144*4096 bf16 = 50331648 B
  u16* xb  = (u16*)(ws + 50331648);                        // 2048*4096 bf16 = 16777216 B (reused as AO)
  u16* qkv = (u16*)(ws + 50331648 + 16777216);             // 2048*6144 bf16 = 25165824 B
  u16* Qr  = (u16*)(ws + 50331648 + 16777216 + 25165824);  // 32*2048*128 bf16
  u16* Kr  = Qr + (size_t)NH * TT * HD;                    // 8*2048*128 bf16
  u16* VT  = Kr + (size_t)NG * TT * HD;                    // 8*128*2048 bf16
  u16* AO  = xb;                                           // alias: xb dead after GEMM1

  cvt_f32_bf16<<<2048, 256, 0, stream>>>(x, xb, TT * DM);
  transpose_cvt<<<dim3(QKVN / 64, DM / 64), 256, 0, stream>>>(w_qkv, wT, DM, QKVN);
  gemm_bt<true><<<dim3(QKVN / 128, TT / 128), 256, 0, stream>>>(xb, wT, qkv, TT, QKVN, DM);
  rope_rearrange<<<(TT * (NH + NG)) / 4, 256, 0, stream>>>(qkv, cosT, sinT, Qr, Kr);
  vtrans<<<dim3(TT / 64, HD / 64, NG), 256, 0, stream>>>(qkv, VT);
  transpose_cvt<<<dim3(DM / 64, DM / 64), 256, 0, stream>>>(w_out, wT, DM, DM);  // after GEMM1: safe reuse
  attn<<<NH * (TT / 128), 256, 0, stream>>>(Qr, Kr, VT, AO);
  gemm_bt<false><<<dim3(DM / 128, TT / 128), 256, 0, stream>>>(AO, wT, out, TT, DM, DM);
}

// Round 3
// 447.378 us; speedup vs baseline: 1.2738x; 1.1027x over previous
//
#include <hip/hip_runtime.h>
#include <cstdint>
#include <cstddef>

// Problem constants
#define TT   2048   // tokens
#define DM   4096   // d_model
#define NH   32     // q heads
#define NG   8      // kv groups
#define HD   128    // head dim
#define QKVN 6144   // (32+16)*128
#define KOFF 4096   // k column offset in qkv
#define VOFF 5120   // v column offset in qkv

typedef __attribute__((ext_vector_type(8))) short bf16x8;   // 8 bf16 (4 VGPRs)
typedef __attribute__((ext_vector_type(4))) float f32x4;    // MFMA 16x16 accumulator
typedef unsigned short u16;

__device__ __forceinline__ u16 f2b(float f) {   // f32 -> bf16 RNE
  unsigned u = __builtin_bit_cast(unsigned, f);
  u += 0x7fffu + ((u >> 16) & 1u);
  return (u16)(u >> 16);
}
__device__ __forceinline__ float b2f(u16 s) {
  unsigned u = ((unsigned)s) << 16;
  return __builtin_bit_cast(float, u);
}

// async global->LDS, 16B per lane; LDS dest = wave-uniform base + lane*16
__device__ __forceinline__ void gload_lds16(const void* g, void* l) {
  __builtin_amdgcn_global_load_lds(
      (const __attribute__((address_space(1))) unsigned int*)g,
      (__attribute__((address_space(3))) unsigned int*)l,
      16, 0, 0);
}

// ---------------- elementwise f32 -> bf16 ----------------
__global__ __launch_bounds__(256) void cvt_f32_bf16(
    const float* __restrict__ src, u16* __restrict__ dst, int n) {
  for (int i = (blockIdx.x * 256 + threadIdx.x) * 4; i < n; i += gridDim.x * 256 * 4) {
    float4 v = *(const float4*)(src + i);
    ushort4 o;
    o.x = f2b(v.x); o.y = f2b(v.y); o.z = f2b(v.z); o.w = f2b(v.w);
    *(ushort4*)(dst + i) = o;
  }
}

// ---------------- transpose + convert: src f32 [R][C] -> dst bf16 [C][R] ----------------
__global__ __launch_bounds__(256) void transpose_cvt(
    const float* __restrict__ src, u16* __restrict__ dst, int R, int C) {
  __shared__ u16 tile[64][66];
  const int rb = blockIdx.y * 64, cb = blockIdx.x * 64;
  const int tid = threadIdx.x;
#pragma unroll
  for (int it = 0; it < 16; ++it) {
    int idx = it * 256 + tid;
    int i = idx >> 6, j = idx & 63;
    tile[i][j] = f2b(src[(size_t)(rb + i) * C + cb + j]);
  }
  __syncthreads();
#pragma unroll
  for (int it = 0; it < 16; ++it) {
    int idx = it * 256 + tid;
    int j = idx >> 6, i = idx & 63;
    dst[(size_t)(cb + j) * R + rb + i] = tile[i][j];
  }
}

// ---------------- bf16 GEMM, phase-split counted-vmcnt template ----------------
// C[M][N] = A[M][K] * Bt[N][K]^T.  BM=128 BN=256 BK=64, 512 thr = 8 waves (2Mx4N),
// per-wave 64x64 (acc 4x4).  2 phases / K-tile, 2 barriers/phase, vmcnt(2) once per
// K-tile (prefetch distance 2: B(u+1) staged in P0, A(u+2) in P1).  Race-free by
// construction: every stage is issued after a global barrier that follows the
// lgkmcnt-drain of all reads of the bytes it overwrites.  LDS tiles XOR-swizzled
// col ^= ((row&7)<<3) via pre-swizzled global source (rule #21).
template <bool OUT_BF16>
__global__ __launch_bounds__(512) void gemm8p(
    const u16* __restrict__ A, const u16* __restrict__ Bt, void* __restrict__ Cout,
    int M, int N, int K, int nbx) {
  __shared__ __align__(16) u16 sA[2][128 * 64];
  __shared__ __align__(16) u16 sB[2][256 * 64];
  const int tid = threadIdx.x;
  const int wid = tid >> 6, lane = tid & 63;
  const int lane15 = lane & 15, laneh = lane >> 4;
  const int wm = wid >> 2, wn = wid & 3;
  // bijective XCD swizzle (grid % 8 == 0); chunk shares A row-panels for L2
  const int cpx = gridDim.x >> 3;
  const int swz = ((int)blockIdx.x & 7) * cpx + ((int)blockIdx.x >> 3);
  const int m0 = (swz / nbx) * 128, n0 = (swz % nbx) * 256;
  const int xorL = (lane15 & 7) << 3;

  f32x4 acc[4][4];
#pragma unroll
  for (int m = 0; m < 4; ++m)
#pragma unroll
    for (int n = 0; n < 4; ++n)
#pragma unroll
      for (int r = 0; r < 4; ++r) acc[m][n][r] = 0.f;

  auto stageA = [&](int buf, int t) {
    const int k0 = t << 6;
#pragma unroll
    for (int i = 0; i < 2; ++i) {
      const int ebase = (wid * 2 + i) * 512;
      const int e = ebase + lane * 8;
      const int row = e >> 6;
      const int col = (e & 63) ^ ((row & 7) << 3);
      gload_lds16(A + (size_t)(m0 + row) * K + k0 + col, &sA[buf][ebase]);
    }
  };
  auto stageB = [&](int buf, int t) {
    const int k0 = t << 6;
#pragma unroll
    for (int i = 0; i < 4; ++i) {
      const int ebase = (wid * 4 + i) * 512;
      const int e = ebase + lane * 8;
      const int row = e >> 6;
      const int col = (e & 63) ^ ((row & 7) << 3);
      gload_lds16(Bt + (size_t)(n0 + row) * K + k0 + col, &sB[buf][ebase]);
    }
  };

  const int NT = K >> 6;
  // prologue: A(0), B(0), A(1) in flight; need A0+B0 landed -> vmcnt(2)
  stageA(0, 0);
  stageB(0, 0);
  stageA(1, 1);
  asm volatile("s_waitcnt vmcnt(2)");
  __builtin_amdgcn_s_barrier();

  for (int u = 0; u < NT; ++u) {
    const int cur = u & 1;
    bf16x8 af[4][2], bfr[4][2];
    // ======== phase 0: load af(all) + bfr(n=0,1); stage B(u+1); MFMA n-half 0 ========
#pragma unroll
    for (int m = 0; m < 4; ++m)
#pragma unroll
      for (int ks = 0; ks < 2; ++ks)
        af[m][ks] = *(const bf16x8*)&sA[cur][(wm * 64 + m * 16 + lane15) * 64 +
                                            ((ks * 32 + laneh * 8) ^ xorL)];
#pragma unroll
    for (int n = 0; n < 2; ++n)
#pragma unroll
      for (int ks = 0; ks < 2; ++ks)
        bfr[n][ks] = *(const bf16x8*)&sB[cur][(wn * 64 + n * 16 + lane15) * 64 +
                                             ((ks * 32 + laneh * 8) ^ xorL)];
    __builtin_amdgcn_sched_barrier(0);
    if (u + 1 < NT) stageB(cur ^ 1, u + 1);   // overwrites B(u-1): drained at (u-1).P1
    __builtin_amdgcn_s_barrier();
    asm volatile("s_waitcnt lgkmcnt(0)");
    __builtin_amdgcn_sched_barrier(0);
    __builtin_amdgcn_s_setprio(1);
#pragma unroll
    for (int ks = 0; ks < 2; ++ks)
#pragma unroll
      for (int m = 0; m < 4; ++m)
#pragma unroll
        for (int n = 0; n < 2; ++n)
          acc[m][n] = __builtin_amdgcn_mfma_f32_16x16x32_bf16(af[m][ks], bfr[n][ks], acc[m][n], 0, 0, 0);
    __builtin_amdgcn_s_setprio(0);
    __builtin_amdgcn_s_barrier();
    // ======== phase 1: load bfr(n=2,3); stage A(u+2); MFMA n-half 1; vmcnt ========
#pragma unroll
    for (int n = 2; n < 4; ++n)
#pragma unroll
      for (int ks = 0; ks < 2; ++ks)
        bfr[n][ks] = *(const bf16x8*)&sB[cur][(wn * 64 + n * 16 + lane15) * 64 +
                                             ((ks * 32 + laneh * 8) ^ xorL)];
    __builtin_amdgcn_sched_barrier(0);
    if (u + 2 < NT) stageA(cur, u + 2);       // overwrites A(u): drained at this P0
    __builtin_amdgcn_s_barrier();
    asm volatile("s_waitcnt lgkmcnt(0)");
    __builtin_amdgcn_sched_barrier(0);
    __builtin_amdgcn_s_setprio(1);
#pragma unroll
    for (int ks = 0; ks < 2; ++ks)
#pragma unroll
      for (int m = 0; m < 4; ++m)
#pragma unroll
        for (int n = 2; n < 4; ++n)
          acc[m][n] = __builtin_amdgcn_mfma_f32_16x16x32_bf16(af[m][ks], bfr[n][ks], acc[m][n], 0, 0, 0);
    __builtin_amdgcn_s_setprio(0);
    // counted wait: everything except A(u+2)'s 2 loads must have landed
    if (u + 2 < NT) asm volatile("s_waitcnt vmcnt(2)");
    else            asm volatile("s_waitcnt vmcnt(0)");
    __builtin_amdgcn_s_barrier();
  }
  // epilogue: D row=(lane>>4)*4+r, col=lane&15
#pragma unroll
  for (int m = 0; m < 4; ++m)
#pragma unroll
    for (int n = 0; n < 4; ++n)
#pragma unroll
      for (int r = 0; r < 4; ++r) {
        const int row = m0 + wm * 64 + m * 16 + laneh * 4 + r;
        const int col = n0 + wn * 64 + n * 16 + lane15;
        const float v = acc[m][n][r];
        if (OUT_BF16) ((u16*)Cout)[(size_t)row * N + col] = f2b(v);
        else          ((float*)Cout)[(size_t)row * N + col] = v;
      }
}

// ---------------- RoPE + rearrange: qkv -> Qr[h][t][d], Kr[g][t][d] ----------------
__global__ __launch_bounds__(256) void rope_rearrange(
    const u16* __restrict__ qkv, const float* __restrict__ cosT,
    const float* __restrict__ sinT, u16* __restrict__ Qr, u16* __restrict__ Kr) {
  const int u = blockIdx.x * 4 + (threadIdx.x >> 6);  // u = e*TT + t, e in [0,40)
  const int lane = threadIdx.x & 63;
  const int t = u & (TT - 1);
  const int e = u >> 11;
  const u16* in;
  u16* outp;
  if (e < NH) {
    in = qkv + (size_t)t * QKVN + e * HD;
    outp = Qr + ((size_t)e * TT + t) * HD;
  } else {
    const int g = e - NH;
    in = qkv + (size_t)t * QKVN + KOFF + g * HD;
    outp = Kr + ((size_t)g * TT + t) * HD;
  }
  const float u1 = b2f(in[lane]), u2 = b2f(in[lane + 64]);
  const float c1 = cosT[t * HD + lane], s1 = sinT[t * HD + lane];
  const float c2 = cosT[t * HD + lane + 64], s2 = sinT[t * HD + lane + 64];
  outp[lane]      = f2b(u1 * c1 - u2 * s1);   // d<64:  u*cos - u[d+64]*sin
  outp[lane + 64] = f2b(u2 * c2 + u1 * s2);   // d>=64: u*cos + u[d-64]*sin
}

// ---------------- V transpose per group: qkv V block -> VT[g][d][t] ----------------
__global__ __launch_bounds__(256) void vtrans(
    const u16* __restrict__ qkv, u16* __restrict__ VT) {
  __shared__ u16 tile[64][66];
  const int g = blockIdx.z;
  const int t0 = blockIdx.x * 64, d0 = blockIdx.y * 64;
  const int tid = threadIdx.x;
#pragma unroll
  for (int it = 0; it < 16; ++it) {
    int idx = it * 256 + tid;
    int i = idx >> 6, j = idx & 63;                       // i: t, j: d
    tile[i][j] = qkv[(size_t)(t0 + i) * QKVN + VOFF + g * HD + d0 + j];
  }
  __syncthreads();
#pragma unroll
  for (int it = 0; it < 16; ++it) {
    int idx = it * 256 + tid;
    int j = idx >> 6, i = idx & 63;
    VT[((size_t)g * HD + d0 + j) * TT + t0 + i] = tile[i][j];
  }
}

// ---------------- causal flash attention (GQA) ----------------
// block = (head h, q-tile qt): 128 q rows; 4 waves x 32 rows; KV tiles of 128
// LDS 64KB (P slab aliases sK after QK^T) -> 2 blocks/CU; all tiles XOR-swizzled
__global__ __launch_bounds__(256) void attn(
    const u16* __restrict__ Qr, const u16* __restrict__ Kr,
    const u16* __restrict__ VT, u16* __restrict__ AO) {
  __shared__ __align__(16) u16 sK[128 * 128];      // [s][d] swizzled; P slab after QK^T
  __shared__ __align__(16) u16 sV[128 * 128];      // [d][s] swizzled
  // XCD-chunked bijective swizzle: 512 blocks = 8 XCDs x 64; each XCD sees 1 KV group
  const int bid = blockIdx.x;
  const int swz = (bid & 7) * 64 + (bid >> 3);
  const int h = swz >> 4, qt = swz & 15;
  const int g = h >> 2;
  const int tid = threadIdx.x, wid = tid >> 6, lane = tid & 63;
  const int lane15 = lane & 15, laneh = lane >> 4;
  const int xorL = (lane15 & 7) << 3;              // read-side swizzle (row = *+lane15)
  const u16* Qh = Qr + (size_t)h * TT * HD;
  const u16* Kg = Kr + (size_t)g * TT * HD;
  const u16* Vg = VT + (size_t)g * HD * TT;

  // Q fragments held in registers: a[j] = Q[row=lane&15][k=(lane>>4)*8+j]
  bf16x8 qf[2][4];
  const int qrow0 = qt * 128 + wid * 32;
#pragma unroll
  for (int m = 0; m < 2; ++m)
#pragma unroll
    for (int ks = 0; ks < 4; ++ks)
      qf[m][ks] = *(const bf16x8*)(Qh + (size_t)(qrow0 + m * 16 + lane15) * HD + ks * 32 + laneh * 8);

  f32x4 acc_o[2][8];
  float mrow[2][4], lrow[2][4];
#pragma unroll
  for (int m = 0; m < 2; ++m) {
#pragma unroll
    for (int n = 0; n < 8; ++n)
#pragma unroll
      for (int r = 0; r < 4; ++r) acc_o[m][n][r] = 0.f;
#pragma unroll
    for (int r = 0; r < 4; ++r) { mrow[m][r] = -1e30f; lrow[m][r] = 0.f; }
  }
  const float scale = 0.08838834764831845f;  // 1/sqrt(128)

  for (int kv = 0; kv <= qt; ++kv) {
    // stage K tile [s][d] and VT tile [d][s]; source col pre-swizzled so that
    // linear LDS write + swizzled read = correct data (involution)
#pragma unroll
    for (int i = 0; i < 8; ++i) {
      const int ebase = (wid * 8 + i) * 512;
      const int e = ebase + lane * 8;
      const int row = e >> 7;
      const int col = (e & 127) ^ ((row & 7) << 3);
      gload_lds16(Kg + (size_t)(kv * 128 + row) * HD + col, &sK[ebase]);
      gload_lds16(Vg + (size_t)row * TT + kv * 128 + col, &sV[ebase]);
    }
    __syncthreads();

    // S = Q K^T
    f32x4 s[2][8];
#pragma unroll
    for (int m = 0; m < 2; ++m)
#pragma unroll
      for (int n = 0; n < 8; ++n)
#pragma unroll
        for (int r = 0; r < 4; ++r) s[m][n][r] = 0.f;
    __builtin_amdgcn_s_setprio(1);
#pragma unroll
    for (int ks = 0; ks < 4; ++ks) {
      bf16x8 kf[8];
#pragma unroll
      for (int n = 0; n < 8; ++n)
        kf[n] = *(const bf16x8*)&sK[(n * 16 + lane15) * 128 + ((ks * 32 + laneh * 8) ^ xorL)];
#pragma unroll
      for (int m = 0; m < 2; ++m)
#pragma unroll
        for (int n = 0; n < 8; ++n)
          s[m][n] = __builtin_amdgcn_mfma_f32_16x16x32_bf16(qf[m][ks], kf[n], s[m][n], 0, 0, 0);
    }
    __builtin_amdgcn_s_setprio(0);
    __syncthreads();   // all waves done reading sK before P overwrites it

    // scale + causal mask (only diagonal tile needs the mask)
    if (kv == qt) {
#pragma unroll
      for (int m = 0; m < 2; ++m)
#pragma unroll
        for (int n = 0; n < 8; ++n)
#pragma unroll
          for (int r = 0; r < 4; ++r) {
            const int ql = wid * 32 + m * 16 + laneh * 4 + r;
            const int sl = n * 16 + lane15;
            s[m][n][r] = (sl > ql) ? -1e30f : s[m][n][r] * scale;
          }
    } else {
#pragma unroll
      for (int m = 0; m < 2; ++m)
#pragma unroll
        for (int n = 0; n < 8; ++n)
#pragma unroll
          for (int r = 0; r < 4; ++r) s[m][n][r] *= scale;
    }
    // online softmax: row lives in 16 lanes sharing (lane>>4); reduce via shfl_xor 1/2/4/8
#pragma unroll
    for (int m = 0; m < 2; ++m)
#pragma unroll
      for (int r = 0; r < 4; ++r) {
        float pm = s[m][0][r];
#pragma unroll
        for (int n = 1; n < 8; ++n) pm = fmaxf(pm, s[m][n][r]);
        pm = fmaxf(pm, __shfl_xor(pm, 1));
        pm = fmaxf(pm, __shfl_xor(pm, 2));
        pm = fmaxf(pm, __shfl_xor(pm, 4));
        pm = fmaxf(pm, __shfl_xor(pm, 8));
        const float mnew = fmaxf(mrow[m][r], pm);
        const float corr = __expf(mrow[m][r] - mnew);
        mrow[m][r] = mnew;
        float ps = 0.f;
#pragma unroll
        for (int n = 0; n < 8; ++n) {
          const float p = __expf(s[m][n][r] - mnew);
          s[m][n][r] = p;
          ps += p;
        }
        ps += __shfl_xor(ps, 1); ps += __shfl_xor(ps, 2);
        ps += __shfl_xor(ps, 4); ps += __shfl_xor(ps, 8);
        lrow[m][r] = lrow[m][r] * corr + ps;
#pragma unroll
        for (int n = 0; n < 8; ++n) acc_o[m][n][r] *= corr;
      }
    // P (D-frag layout) -> per-wave 32-row slab aliased into sK (swizzled write)
#pragma unroll
    for (int m = 0; m < 2; ++m)
#pragma unroll
      for (int n = 0; n < 8; ++n)
#pragma unroll
        for (int r = 0; r < 4; ++r) {
          const int prow = wid * 32 + m * 16 + laneh * 4 + r;
          const int pcol = (n * 16 + lane15) ^ (((laneh * 4 + r) & 7) << 3);
          sK[prow * 128 + pcol] = f2b(s[m][n][r]);
        }
    // PV: O += P @ V   (pf from own slab; vf from sV; both swizzled reads)
    __builtin_amdgcn_s_setprio(1);
#pragma unroll
    for (int ks = 0; ks < 4; ++ks) {
      bf16x8 pf[2], vf[8];
#pragma unroll
      for (int m = 0; m < 2; ++m)
        pf[m] = *(const bf16x8*)&sK[(wid * 32 + m * 16 + lane15) * 128 + ((ks * 32 + laneh * 8) ^ xorL)];
#pragma unroll
      for (int n = 0; n < 8; ++n)
        vf[n] = *(const bf16x8*)&sV[(n * 16 + lane15) * 128 + ((ks * 32 + laneh * 8) ^ xorL)];
#pragma unroll
      for (int m = 0; m < 2; ++m)
#pragma unroll
        for (int n = 0; n < 8; ++n)
          acc_o[m][n] = __builtin_amdgcn_mfma_f32_16x16x32_bf16(pf[m], vf[n], acc_o[m][n], 0, 0, 0);
    }
    __builtin_amdgcn_s_setprio(0);
    __syncthreads();  // all waves done with sK(P)/sV before next stage overwrites
  }
  // epilogue: AO[t][h*128+d] = O / l
#pragma unroll
  for (int m = 0; m < 2; ++m) {
    float inv[4];
#pragma unroll
    for (int r = 0; r < 4; ++r) inv[r] = 1.f / lrow[m][r];
#pragma unroll
    for (int n = 0; n < 8; ++n)
#pragma unroll
      for (int r = 0; r < 4; ++r) {
        const int trow = qt * 128 + wid * 32 + m * 16 + laneh * 4 + r;
        AO[(size_t)trow * DM + h * HD + n * 16 + lane15] = f2b(acc_o[m][n][r] * inv[r]);
      }
  }
}

// ---------------- launch ----------------
extern "C" void kernel_launch(void* const* d_in, const int* in_sizes, int n_in,
                              void* d_out, int out_size, void* d_ws, size_t ws_size,
                              hipStream_t stream) {
  const float* x     = (const float*)d_in[0];
  const float* w_qkv = (const float*)d_in[1];
  const float* w_out = (const float*)d_in[2];
  const float* cosT  = (const float*)d_in[3];
  const float* sinT  = (const float*)d_in[4];
  // d_in[5] (mask) unused: causal mask computed analytically
  float* out = (float*)d_out;

  char* ws = (char*)d_ws;
  // layout (bytes): wT region reused for wqT then woT (stream-ordered)
  u16* wT  = (u16*)(ws);                                   // 6144*4096 bf16 = 50331648 B
  u16* xb  = (u16*)(ws + 50331648);                        // 2048*4096 bf16 = 16777216 B (reused as AO)
  u16* qkv = (u16*)(ws + 50331648 + 16777216);             // 2048*6144 bf16 = 25165824 B
  u16* Qr  = (u16*)(ws + 50331648 + 16777216 + 25165824);  // 32*2048*128 bf16
  u16* Kr  = Qr + (size_t)NH * TT * HD;                    // 8*2048*128 bf16
  u16* VT  = Kr + (size_t)NG * TT * HD;                    // 8*128*2048 bf16
  u16* AO  = xb;                                           // alias: xb dead after GEMM1

  cvt_f32_bf16<<<2048, 256, 0, stream>>>(x, xb, TT * DM);
  transpose_cvt<<<dim3(QKVN / 64, DM / 64), 256, 0, stream>>>(w_qkv, wT, DM, QKVN);
  gemm8p<true><<<dim3((TT / 128) * (QKVN / 256)), 512, 0, stream>>>(
      xb, wT, qkv, TT, QKVN, DM, QKVN / 256);
  rope_rearrange<<<(TT * (NH + NG)) / 4, 256, 0, stream>>>(qkv, cosT, sinT, Qr, Kr);
  vtrans<<<dim3(TT / 64, HD / 64, NG), 256, 0, stream>>>(qkv, VT);
  transpose_cvt<<<dim3(DM / 64, DM / 64), 256, 0, stream>>>(w_out, wT, DM, DM);  // after GEMM1: safe reuse
  attn<<<NH * (TT / 128), 256, 0, stream>>>(Qr, Kr, VT, AO);
  gemm8p<false><<<dim3((TT / 128) * (DM / 256)), 512, 0, stream>>>(
      AO, wT, out, TT, DM, DM, DM / 256);
}

// Round 4
// 372.108 us; speedup vs baseline: 1.5315x; 1.2023x over previous
//
#include <hip/hip_runtime.h>
#include <cstdint>
#include <cstddef>

// Problem constants
#define TT   2048   // tokens
#define DM   4096   // d_model
#define NH   32     // q heads
#define NG   8      // kv groups
#define HD   128    // head dim
#define QKVN 6144   // (32+16)*128
#define KOFF 4096   // k column offset in qkv
#define VOFF 5120   // v column offset in qkv

typedef __attribute__((ext_vector_type(8))) short bf16x8;   // 8 bf16 (4 VGPRs)
typedef __attribute__((ext_vector_type(4))) float f32x4;    // MFMA 16x16 accumulator
typedef unsigned short u16;

__device__ __forceinline__ u16 f2b(float f) {   // f32 -> bf16 RNE
  unsigned u = __builtin_bit_cast(unsigned, f);
  u += 0x7fffu + ((u >> 16) & 1u);
  return (u16)(u >> 16);
}
__device__ __forceinline__ float b2f(u16 s) {
  unsigned u = ((unsigned)s) << 16;
  return __builtin_bit_cast(float, u);
}

// async global->LDS, 16B per lane; LDS dest = wave-uniform base + lane*16
__device__ __forceinline__ void gload_lds16(const void* g, void* l) {
  __builtin_amdgcn_global_load_lds(
      (const __attribute__((address_space(1))) unsigned int*)g,
      (__attribute__((address_space(3))) unsigned int*)l,
      16, 0, 0);
}

// ---------------- elementwise f32 -> bf16 ----------------
__global__ __launch_bounds__(256) void cvt_f32_bf16(
    const float* __restrict__ src, u16* __restrict__ dst, int n) {
  for (int i = (blockIdx.x * 256 + threadIdx.x) * 4; i < n; i += gridDim.x * 256 * 4) {
    float4 v = *(const float4*)(src + i);
    ushort4 o;
    o.x = f2b(v.x); o.y = f2b(v.y); o.z = f2b(v.z); o.w = f2b(v.w);
    *(ushort4*)(dst + i) = o;
  }
}

// ---------------- transpose + convert: src f32 [R][C] -> dst bf16 [C][R] ----------------
__global__ __launch_bounds__(256) void transpose_cvt(
    const float* __restrict__ src, u16* __restrict__ dst, int R, int C) {
  __shared__ u16 tile[64][66];
  const int rb = blockIdx.y * 64, cb = blockIdx.x * 64;
  const int tid = threadIdx.x;
#pragma unroll
  for (int it = 0; it < 16; ++it) {
    int idx = it * 256 + tid;
    int i = idx >> 6, j = idx & 63;
    tile[i][j] = f2b(src[(size_t)(rb + i) * C + cb + j]);
  }
  __syncthreads();
#pragma unroll
  for (int it = 0; it < 16; ++it) {
    int idx = it * 256 + tid;
    int j = idx >> 6, i = idx & 63;
    dst[(size_t)(cb + j) * R + rb + i] = tile[i][j];
  }
}

// ---------------- bf16 GEMM, phase-split counted-vmcnt template ----------------
// C[M][N] = A[M][K] * Bt[N][K]^T.  BM=128 BN=256 BK=64, 512 thr = 8 waves (2Mx4N),
// per-wave 64x64 (acc 4x4).  2 phases / K-tile, vmcnt(2) once per K-tile.
template <bool OUT_BF16>
__global__ __launch_bounds__(512) void gemm8p(
    const u16* __restrict__ A, const u16* __restrict__ Bt, void* __restrict__ Cout,
    int M, int N, int K, int nbx) {
  __shared__ __align__(16) u16 sA[2][128 * 64];
  __shared__ __align__(16) u16 sB[2][256 * 64];
  const int tid = threadIdx.x;
  const int wid = tid >> 6, lane = tid & 63;
  const int lane15 = lane & 15, laneh = lane >> 4;
  const int wm = wid >> 2, wn = wid & 3;
  // bijective XCD swizzle (grid % 8 == 0); chunk shares A row-panels for L2
  const int cpx = gridDim.x >> 3;
  const int swz = ((int)blockIdx.x & 7) * cpx + ((int)blockIdx.x >> 3);
  const int m0 = (swz / nbx) * 128, n0 = (swz % nbx) * 256;
  const int xorL = (lane15 & 7) << 3;

  f32x4 acc[4][4];
#pragma unroll
  for (int m = 0; m < 4; ++m)
#pragma unroll
    for (int n = 0; n < 4; ++n)
#pragma unroll
      for (int r = 0; r < 4; ++r) acc[m][n][r] = 0.f;

  auto stageA = [&](int buf, int t) {
    const int k0 = t << 6;
#pragma unroll
    for (int i = 0; i < 2; ++i) {
      const int ebase = (wid * 2 + i) * 512;
      const int e = ebase + lane * 8;
      const int row = e >> 6;
      const int col = (e & 63) ^ ((row & 7) << 3);
      gload_lds16(A + (size_t)(m0 + row) * K + k0 + col, &sA[buf][ebase]);
    }
  };
  auto stageB = [&](int buf, int t) {
    const int k0 = t << 6;
#pragma unroll
    for (int i = 0; i < 4; ++i) {
      const int ebase = (wid * 4 + i) * 512;
      const int e = ebase + lane * 8;
      const int row = e >> 6;
      const int col = (e & 63) ^ ((row & 7) << 3);
      gload_lds16(Bt + (size_t)(n0 + row) * K + k0 + col, &sB[buf][ebase]);
    }
  };

  const int NT = K >> 6;
  // prologue: A(0), B(0), A(1) in flight; need A0+B0 landed -> vmcnt(2)
  stageA(0, 0);
  stageB(0, 0);
  stageA(1, 1);
  asm volatile("s_waitcnt vmcnt(2)");
  __builtin_amdgcn_s_barrier();

  for (int u = 0; u < NT; ++u) {
    const int cur = u & 1;
    bf16x8 af[4][2], bfr[4][2];
    // ======== phase 0: load af(all) + bfr(n=0,1); stage B(u+1); MFMA n-half 0 ========
#pragma unroll
    for (int m = 0; m < 4; ++m)
#pragma unroll
      for (int ks = 0; ks < 2; ++ks)
        af[m][ks] = *(const bf16x8*)&sA[cur][(wm * 64 + m * 16 + lane15) * 64 +
                                            ((ks * 32 + laneh * 8) ^ xorL)];
#pragma unroll
    for (int n = 0; n < 2; ++n)
#pragma unroll
      for (int ks = 0; ks < 2; ++ks)
        bfr[n][ks] = *(const bf16x8*)&sB[cur][(wn * 64 + n * 16 + lane15) * 64 +
                                             ((ks * 32 + laneh * 8) ^ xorL)];
    __builtin_amdgcn_sched_barrier(0);
    if (u + 1 < NT) stageB(cur ^ 1, u + 1);   // overwrites B(u-1): drained at (u-1).P1
    __builtin_amdgcn_s_barrier();
    asm volatile("s_waitcnt lgkmcnt(0)");
    __builtin_amdgcn_sched_barrier(0);
    __builtin_amdgcn_s_setprio(1);
#pragma unroll
    for (int ks = 0; ks < 2; ++ks)
#pragma unroll
      for (int m = 0; m < 4; ++m)
#pragma unroll
        for (int n = 0; n < 2; ++n)
          acc[m][n] = __builtin_amdgcn_mfma_f32_16x16x32_bf16(af[m][ks], bfr[n][ks], acc[m][n], 0, 0, 0);
    __builtin_amdgcn_s_setprio(0);
    __builtin_amdgcn_s_barrier();
    // ======== phase 1: load bfr(n=2,3); stage A(u+2); MFMA n-half 1; vmcnt ========
#pragma unroll
    for (int n = 2; n < 4; ++n)
#pragma unroll
      for (int ks = 0; ks < 2; ++ks)
        bfr[n][ks] = *(const bf16x8*)&sB[cur][(wn * 64 + n * 16 + lane15) * 64 +
                                             ((ks * 32 + laneh * 8) ^ xorL)];
    __builtin_amdgcn_sched_barrier(0);
    if (u + 2 < NT) stageA(cur, u + 2);       // overwrites A(u): drained at this P0
    __builtin_amdgcn_s_barrier();
    asm volatile("s_waitcnt lgkmcnt(0)");
    __builtin_amdgcn_sched_barrier(0);
    __builtin_amdgcn_s_setprio(1);
#pragma unroll
    for (int ks = 0; ks < 2; ++ks)
#pragma unroll
      for (int m = 0; m < 4; ++m)
#pragma unroll
        for (int n = 2; n < 4; ++n)
          acc[m][n] = __builtin_amdgcn_mfma_f32_16x16x32_bf16(af[m][ks], bfr[n][ks], acc[m][n], 0, 0, 0);
    __builtin_amdgcn_s_setprio(0);
    // counted wait: everything except A(u+2)'s 2 loads must have landed
    if (u + 2 < NT) asm volatile("s_waitcnt vmcnt(2)");
    else            asm volatile("s_waitcnt vmcnt(0)");
    __builtin_amdgcn_s_barrier();
  }
  // epilogue: D row=(lane>>4)*4+r, col=lane&15
#pragma unroll
  for (int m = 0; m < 4; ++m)
#pragma unroll
    for (int n = 0; n < 4; ++n)
#pragma unroll
      for (int r = 0; r < 4; ++r) {
        const int row = m0 + wm * 64 + m * 16 + laneh * 4 + r;
        const int col = n0 + wn * 64 + n * 16 + lane15;
        const float v = acc[m][n][r];
        if (OUT_BF16) ((u16*)Cout)[(size_t)row * N + col] = f2b(v);
        else          ((float*)Cout)[(size_t)row * N + col] = v;
      }
}

// ---------------- RoPE + rearrange: qkv -> Qr[h][t][d], Kr[g][t][d] ----------------
__global__ __launch_bounds__(256) void rope_rearrange(
    const u16* __restrict__ qkv, const float* __restrict__ cosT,
    const float* __restrict__ sinT, u16* __restrict__ Qr, u16* __restrict__ Kr) {
  const int u = blockIdx.x * 4 + (threadIdx.x >> 6);  // u = e*TT + t, e in [0,40)
  const int lane = threadIdx.x & 63;
  const int t = u & (TT - 1);
  const int e = u >> 11;
  const u16* in;
  u16* outp;
  if (e < NH) {
    in = qkv + (size_t)t * QKVN + e * HD;
    outp = Qr + ((size_t)e * TT + t) * HD;
  } else {
    const int g = e - NH;
    in = qkv + (size_t)t * QKVN + KOFF + g * HD;
    outp = Kr + ((size_t)g * TT + t) * HD;
  }
  const float u1 = b2f(in[lane]), u2 = b2f(in[lane + 64]);
  const float c1 = cosT[t * HD + lane], s1 = sinT[t * HD + lane];
  const float c2 = cosT[t * HD + lane + 64], s2 = sinT[t * HD + lane + 64];
  outp[lane]      = f2b(u1 * c1 - u2 * s1);   // d<64:  u*cos - u[d+64]*sin
  outp[lane + 64] = f2b(u2 * c2 + u1 * s2);   // d>=64: u*cos + u[d-64]*sin
}

// ---------------- V transpose per group: qkv V block -> VT[g][d][t] ----------------
__global__ __launch_bounds__(256) void vtrans(
    const u16* __restrict__ qkv, u16* __restrict__ VT) {
  __shared__ u16 tile[64][66];
  const int g = blockIdx.z;
  const int t0 = blockIdx.x * 64, d0 = blockIdx.y * 64;
  const int tid = threadIdx.x;
#pragma unroll
  for (int it = 0; it < 16; ++it) {
    int idx = it * 256 + tid;
    int i = idx >> 6, j = idx & 63;                       // i: t, j: d
    tile[i][j] = qkv[(size_t)(t0 + i) * QKVN + VOFF + g * HD + d0 + j];
  }
  __syncthreads();
#pragma unroll
  for (int it = 0; it < 16; ++it) {
    int idx = it * 256 + tid;
    int j = idx >> 6, i = idx & 63;
    VT[((size_t)g * HD + d0 + j) * TT + t0 + i] = tile[i][j];
  }
}

// ---------------- causal flash attention (GQA), balanced pairing ----------------
// Block = (head h, pair p): processes q-tiles p and 15-p sequentially -> exactly
// 17 KV-tile iterations per block.  Grid = 32*8 = 256 (1 block/CU, no tail).
// 512 thr = 8 waves, each wave owns 16 q-rows.  KV tiles 128x128 in 64KB LDS,
// XOR-swizzled (pre-swizzled global source, rule #21); P slab aliases sK.
__global__ __launch_bounds__(512) void attn(
    const u16* __restrict__ Qr, const u16* __restrict__ Kr,
    const u16* __restrict__ VT, u16* __restrict__ AO) {
  __shared__ __align__(16) u16 sK[128 * 128];      // [s][d] swizzled; P slab after QK^T
  __shared__ __align__(16) u16 sV[128 * 128];      // [d][s] swizzled
  // XCD-chunked bijective swizzle: 256 blocks = 8 XCDs x 32; chunk c = heads 4c..4c+3
  // = exactly KV group c -> each XCD's L2 sees one group's K/V (1MB).
  const int bid = blockIdx.x;
  const int swz = (bid & 7) * 32 + (bid >> 3);
  const int h = swz >> 3, p = swz & 7;
  const int g = h >> 2;
  const int tid = threadIdx.x, wid = tid >> 6, lane = tid & 63;
  const int lane15 = lane & 15, laneh = lane >> 4;
  const int xorL = (lane15 & 7) << 3;              // read-side swizzle (row = *+lane15)
  const u16* Qh = Qr + (size_t)h * TT * HD;
  const u16* Kg = Kr + (size_t)g * TT * HD;
  const u16* Vg = VT + (size_t)g * HD * TT;
  const float scale = 0.08838834764831845f;        // 1/sqrt(128)

  for (int pass = 0; pass < 2; ++pass) {
    const int qt = pass ? (15 - p) : p;
    // Q fragments for this q-tile: wave owns rows [qt*128 + wid*16, +16)
    bf16x8 qf[4];
    const int qrow0 = qt * 128 + wid * 16;
#pragma unroll
    for (int ks = 0; ks < 4; ++ks)
      qf[ks] = *(const bf16x8*)(Qh + (size_t)(qrow0 + lane15) * HD + ks * 32 + laneh * 8);

    f32x4 acc_o[8];
    float mrow[4], lrow[4];
#pragma unroll
    for (int n = 0; n < 8; ++n)
#pragma unroll
      for (int r = 0; r < 4; ++r) acc_o[n][r] = 0.f;
#pragma unroll
    for (int r = 0; r < 4; ++r) { mrow[r] = -1e30f; lrow[r] = 0.f; }

    for (int kv = 0; kv <= qt; ++kv) {
      // stage K tile [s][d] and VT tile [d][s]; source col pre-swizzled
#pragma unroll
      for (int i = 0; i < 4; ++i) {
        const int ebase = (wid * 4 + i) * 512;
        const int e = ebase + lane * 8;
        const int row = e >> 7;
        const int col = (e & 127) ^ ((row & 7) << 3);
        gload_lds16(Kg + (size_t)(kv * 128 + row) * HD + col, &sK[ebase]);
        gload_lds16(Vg + (size_t)row * TT + kv * 128 + col, &sV[ebase]);
      }
      __syncthreads();

      // S = Q K^T  (1 m-frag x 8 n-frags)
      f32x4 s[8];
#pragma unroll
      for (int n = 0; n < 8; ++n)
#pragma unroll
        for (int r = 0; r < 4; ++r) s[n][r] = 0.f;
      __builtin_amdgcn_s_setprio(1);
#pragma unroll
      for (int ks = 0; ks < 4; ++ks) {
        bf16x8 kf[8];
#pragma unroll
        for (int n = 0; n < 8; ++n)
          kf[n] = *(const bf16x8*)&sK[(n * 16 + lane15) * 128 + ((ks * 32 + laneh * 8) ^ xorL)];
#pragma unroll
        for (int n = 0; n < 8; ++n)
          s[n] = __builtin_amdgcn_mfma_f32_16x16x32_bf16(qf[ks], kf[n], s[n], 0, 0, 0);
      }
      __builtin_amdgcn_s_setprio(0);
      __syncthreads();   // all waves done reading sK before P overwrites it

      // scale + causal mask (only diagonal tile needs the mask)
      if (kv == qt) {
#pragma unroll
        for (int n = 0; n < 8; ++n)
#pragma unroll
          for (int r = 0; r < 4; ++r) {
            const int ql = wid * 16 + laneh * 4 + r;
            const int sl = n * 16 + lane15;
            s[n][r] = (sl > ql) ? -1e30f : s[n][r] * scale;
          }
      } else {
#pragma unroll
        for (int n = 0; n < 8; ++n)
#pragma unroll
          for (int r = 0; r < 4; ++r) s[n][r] *= scale;
      }
      // online softmax: row lives in the 16 lanes sharing laneh; reduce via shfl_xor
#pragma unroll
      for (int r = 0; r < 4; ++r) {
        float pm = s[0][r];
#pragma unroll
        for (int n = 1; n < 8; ++n) pm = fmaxf(pm, s[n][r]);
        pm = fmaxf(pm, __shfl_xor(pm, 1));
        pm = fmaxf(pm, __shfl_xor(pm, 2));
        pm = fmaxf(pm, __shfl_xor(pm, 4));
        pm = fmaxf(pm, __shfl_xor(pm, 8));
        const float mnew = fmaxf(mrow[r], pm);
        const float corr = __expf(mrow[r] - mnew);
        mrow[r] = mnew;
        float ps = 0.f;
#pragma unroll
        for (int n = 0; n < 8; ++n) {
          const float pr = __expf(s[n][r] - mnew);
          s[n][r] = pr;
          ps += pr;
        }
        ps += __shfl_xor(ps, 1); ps += __shfl_xor(ps, 2);
        ps += __shfl_xor(ps, 4); ps += __shfl_xor(ps, 8);
        lrow[r] = lrow[r] * corr + ps;
#pragma unroll
        for (int n = 0; n < 8; ++n) acc_o[n][r] *= corr;
      }
      // P (D-frag layout) -> wave's 16-row slab aliased into sK (swizzled write)
#pragma unroll
      for (int n = 0; n < 8; ++n)
#pragma unroll
        for (int r = 0; r < 4; ++r) {
          const int prow = wid * 16 + laneh * 4 + r;
          const int pcol = (n * 16 + lane15) ^ (((laneh * 4 + r) & 7) << 3);
          sK[prow * 128 + pcol] = f2b(s[n][r]);
        }
      // PV: O += P @ V   (pf from own slab; vf from sV; both swizzled reads)
      __builtin_amdgcn_s_setprio(1);
#pragma unroll
      for (int ks = 0; ks < 4; ++ks) {
        bf16x8 pf, vf[8];
        pf = *(const bf16x8*)&sK[(wid * 16 + lane15) * 128 + ((ks * 32 + laneh * 8) ^ xorL)];
#pragma unroll
        for (int n = 0; n < 8; ++n)
          vf[n] = *(const bf16x8*)&sV[(n * 16 + lane15) * 128 + ((ks * 32 + laneh * 8) ^ xorL)];
#pragma unroll
        for (int n = 0; n < 8; ++n)
          acc_o[n] = __builtin_amdgcn_mfma_f32_16x16x32_bf16(pf, vf[n], acc_o[n], 0, 0, 0);
      }
      __builtin_amdgcn_s_setprio(0);
      __syncthreads();  // all waves done with sK(P)/sV before next stage overwrites
    }
    // epilogue for this q-tile: AO[t][h*128+d] = O / l
    float inv[4];
#pragma unroll
    for (int r = 0; r < 4; ++r) inv[r] = 1.f / lrow[r];
#pragma unroll
    for (int n = 0; n < 8; ++n)
#pragma unroll
      for (int r = 0; r < 4; ++r) {
        const int trow = qt * 128 + wid * 16 + laneh * 4 + r;
        AO[(size_t)trow * DM + h * HD + n * 16 + lane15] = f2b(acc_o[n][r] * inv[r]);
      }
  }
}

// ---------------- launch ----------------
extern "C" void kernel_launch(void* const* d_in, const int* in_sizes, int n_in,
                              void* d_out, int out_size, void* d_ws, size_t ws_size,
                              hipStream_t stream) {
  const float* x     = (const float*)d_in[0];
  const float* w_qkv = (const float*)d_in[1];
  const float* w_out = (const float*)d_in[2];
  const float* cosT  = (const float*)d_in[3];
  const float* sinT  = (const float*)d_in[4];
  // d_in[5] (mask) unused: causal mask computed analytically
  float* out = (float*)d_out;

  char* ws = (char*)d_ws;
  // layout (bytes): wT region reused for wqT then woT (stream-ordered)
  u16* wT  = (u16*)(ws);                                   // 6144*4096 bf16 = 50331648 B
  u16* xb  = (u16*)(ws + 50331648);                        // 2048*4096 bf16 = 16777216 B (reused as AO)
  u16* qkv = (u16*)(ws + 50331648 + 16777216);             // 2048*6144 bf16 = 25165824 B
  u16* Qr  = (u16*)(ws + 50331648 + 16777216 + 25165824);  // 32*2048*128 bf16
  u16* Kr  = Qr + (size_t)NH * TT * HD;                    // 8*2048*128 bf16
  u16* VT  = Kr + (size_t)NG * TT * HD;                    // 8*128*2048 bf16
  u16* AO  = xb;                                           // alias: xb dead after GEMM1

  cvt_f32_bf16<<<2048, 256, 0, stream>>>(x, xb, TT * DM);
  transpose_cvt<<<dim3(QKVN / 64, DM / 64), 256, 0, stream>>>(w_qkv, wT, DM, QKVN);
  gemm8p<true><<<dim3((TT / 128) * (QKVN / 256)), 512, 0, stream>>>(
      xb, wT, qkv, TT, QKVN, DM, QKVN / 256);
  rope_rearrange<<<(TT * (NH + NG)) / 4, 256, 0, stream>>>(qkv, cosT, sinT, Qr, Kr);
  vtrans<<<dim3(TT / 64, HD / 64, NG), 256, 0, stream>>>(qkv, VT);
  transpose_cvt<<<dim3(DM / 64, DM / 64), 256, 0, stream>>>(w_out, wT, DM, DM);  // after GEMM1: safe reuse
  attn<<<NH * 8, 512, 0, stream>>>(Qr, Kr, VT, AO);
  gemm8p<false><<<dim3((TT / 128) * (DM / 256)), 512, 0, stream>>>(
      AO, wT, out, TT, DM, DM, DM / 256);
}

// Round 5
// 329.463 us; speedup vs baseline: 1.7297x; 1.1294x over previous
//
#include <hip/hip_runtime.h>
#include <cstdint>
#include <cstddef>

// Problem constants
#define TT   2048   // tokens
#define DM   4096   // d_model
#define NH   32     // q heads
#define NG   8      // kv groups
#define HD   128    // head dim
#define QKVN 6144   // (32+16)*128
#define KOFF 4096   // k column offset in qkv
#define VOFF 5120   // v column offset in qkv

typedef __attribute__((ext_vector_type(8))) short bf16x8;   // 8 bf16 (4 VGPRs)
typedef __attribute__((ext_vector_type(4))) float f32x4;    // MFMA 16x16 accumulator
typedef unsigned short u16;

__device__ __forceinline__ u16 f2b(float f) {   // f32 -> bf16 RNE
  unsigned u = __builtin_bit_cast(unsigned, f);
  u += 0x7fffu + ((u >> 16) & 1u);
  return (u16)(u >> 16);
}
__device__ __forceinline__ float b2f(u16 s) {
  unsigned u = ((unsigned)s) << 16;
  return __builtin_bit_cast(float, u);
}

// async global->LDS, 16B per lane; LDS dest = wave-uniform base + lane*16
__device__ __forceinline__ void gload_lds16(const void* g, void* l) {
  __builtin_amdgcn_global_load_lds(
      (const __attribute__((address_space(1))) unsigned int*)g,
      (__attribute__((address_space(3))) unsigned int*)l,
      16, 0, 0);
}

// ---------------- elementwise f32 -> bf16 ----------------
__global__ __launch_bounds__(256) void cvt_f32_bf16(
    const float* __restrict__ src, u16* __restrict__ dst, int n) {
  for (int i = (blockIdx.x * 256 + threadIdx.x) * 4; i < n; i += gridDim.x * 256 * 4) {
    float4 v = *(const float4*)(src + i);
    ushort4 o;
    o.x = f2b(v.x); o.y = f2b(v.y); o.z = f2b(v.z); o.w = f2b(v.w);
    *(ushort4*)(dst + i) = o;
  }
}

// ---------------- transpose + convert: src f32 [R][C] -> dst bf16 [C][R] ----------------
__global__ __launch_bounds__(256) void transpose_cvt(
    const float* __restrict__ src, u16* __restrict__ dst, int R, int C) {
  __shared__ u16 tile[64][66];
  const int rb = blockIdx.y * 64, cb = blockIdx.x * 64;
  const int tid = threadIdx.x;
#pragma unroll
  for (int it = 0; it < 16; ++it) {
    int idx = it * 256 + tid;
    int i = idx >> 6, j = idx & 63;
    tile[i][j] = f2b(src[(size_t)(rb + i) * C + cb + j]);
  }
  __syncthreads();
#pragma unroll
  for (int it = 0; it < 16; ++it) {
    int idx = it * 256 + tid;
    int j = idx >> 6, i = idx & 63;
    dst[(size_t)(cb + j) * R + rb + i] = tile[i][j];
  }
}

// ---------------- bf16 GEMM, phase-split counted-vmcnt template ----------------
// C[M][N] = A[M][K] * Bt[N][K]^T.  BM=128, BN=WN*64, BK=64, 512 thr = 8 waves
// (2Mx4N), per-wave 64 x WN*16 (acc 4xWN).  2 phases / K-tile, vmcnt(2) once per
// K-tile (prefetch distance 2: B(u+1) staged in P0, A(u+2) in P1).  Race-free by
// construction: every stage is issued after a barrier that follows the drain of
// all reads of the bytes it overwrites.  LDS XOR-swizzled col ^= ((row&7)<<3)
// via pre-swizzled global source (rule #21).
template <int WN, bool OUT_BF16>
__global__ __launch_bounds__(512) void gemm8p(
    const u16* __restrict__ A, const u16* __restrict__ Bt, void* __restrict__ Cout,
    int M, int N, int K, int nbx) {
  __shared__ __align__(16) u16 sA[2][128 * 64];
  __shared__ __align__(16) u16 sB[2][WN * 64 * 64];
  const int tid = threadIdx.x;
  const int wid = tid >> 6, lane = tid & 63;
  const int lane15 = lane & 15, laneh = lane >> 4;
  const int wm = wid >> 2, wn = wid & 3;
  // bijective XCD swizzle (grid % 8 == 0); chunk shares A row-panels for L2
  const int cpx = gridDim.x >> 3;
  const int swz = ((int)blockIdx.x & 7) * cpx + ((int)blockIdx.x >> 3);
  const int m0 = (swz / nbx) * 128, n0 = (swz % nbx) * (WN * 64);
  const int xorL = (lane15 & 7) << 3;

  f32x4 acc[4][WN];
#pragma unroll
  for (int m = 0; m < 4; ++m)
#pragma unroll
    for (int n = 0; n < WN; ++n)
#pragma unroll
      for (int r = 0; r < 4; ++r) acc[m][n][r] = 0.f;

  auto stageA = [&](int buf, int t) {
    const int k0 = t << 6;
#pragma unroll
    for (int i = 0; i < 2; ++i) {
      const int ebase = (wid * 2 + i) * 512;
      const int e = ebase + lane * 8;
      const int row = e >> 6;
      const int col = (e & 63) ^ ((row & 7) << 3);
      gload_lds16(A + (size_t)(m0 + row) * K + k0 + col, &sA[buf][ebase]);
    }
  };
  auto stageB = [&](int buf, int t) {
    const int k0 = t << 6;
#pragma unroll
    for (int i = 0; i < WN; ++i) {
      const int ebase = (wid * WN + i) * 512;
      const int e = ebase + lane * 8;
      const int row = e >> 6;
      const int col = (e & 63) ^ ((row & 7) << 3);
      gload_lds16(Bt + (size_t)(n0 + row) * K + k0 + col, &sB[buf][ebase]);
    }
  };

  const int NT = K >> 6;
  // prologue: A(0), B(0), A(1) in flight; need A0+B0 landed -> vmcnt(2)
  stageA(0, 0);
  stageB(0, 0);
  stageA(1, 1);
  asm volatile("s_waitcnt vmcnt(2)");
  __builtin_amdgcn_s_barrier();

  for (int u = 0; u < NT; ++u) {
    const int cur = u & 1;
    bf16x8 af[4][2], bfr[WN][2];
    // ==== phase 0: load af(all) + bfr(first half); stage B(u+1); MFMA half 0 ====
#pragma unroll
    for (int m = 0; m < 4; ++m)
#pragma unroll
      for (int ks = 0; ks < 2; ++ks)
        af[m][ks] = *(const bf16x8*)&sA[cur][(wm * 64 + m * 16 + lane15) * 64 +
                                            ((ks * 32 + laneh * 8) ^ xorL)];
#pragma unroll
    for (int n = 0; n < WN / 2; ++n)
#pragma unroll
      for (int ks = 0; ks < 2; ++ks)
        bfr[n][ks] = *(const bf16x8*)&sB[cur][(wn * (WN * 16) + n * 16 + lane15) * 64 +
                                             ((ks * 32 + laneh * 8) ^ xorL)];
    __builtin_amdgcn_sched_barrier(0);
    if (u + 1 < NT) stageB(cur ^ 1, u + 1);   // overwrites B(u-1): drained at (u-1).P1
    __builtin_amdgcn_s_barrier();
    asm volatile("s_waitcnt lgkmcnt(0)");
    __builtin_amdgcn_sched_barrier(0);
    __builtin_amdgcn_s_setprio(1);
#pragma unroll
    for (int ks = 0; ks < 2; ++ks)
#pragma unroll
      for (int m = 0; m < 4; ++m)
#pragma unroll
        for (int n = 0; n < WN / 2; ++n)
          acc[m][n] = __builtin_amdgcn_mfma_f32_16x16x32_bf16(af[m][ks], bfr[n][ks], acc[m][n], 0, 0, 0);
    __builtin_amdgcn_s_setprio(0);
    __builtin_amdgcn_s_barrier();
    // ==== phase 1: load bfr(second half); stage A(u+2); MFMA half 1; vmcnt ====
#pragma unroll
    for (int n = WN / 2; n < WN; ++n)
#pragma unroll
      for (int ks = 0; ks < 2; ++ks)
        bfr[n][ks] = *(const bf16x8*)&sB[cur][(wn * (WN * 16) + n * 16 + lane15) * 64 +
                                             ((ks * 32 + laneh * 8) ^ xorL)];
    __builtin_amdgcn_sched_barrier(0);
    if (u + 2 < NT) stageA(cur, u + 2);       // overwrites A(u): drained at this P0
    __builtin_amdgcn_s_barrier();
    asm volatile("s_waitcnt lgkmcnt(0)");
    __builtin_amdgcn_sched_barrier(0);
    __builtin_amdgcn_s_setprio(1);
#pragma unroll
    for (int ks = 0; ks < 2; ++ks)
#pragma unroll
      for (int m = 0; m < 4; ++m)
#pragma unroll
        for (int n = WN / 2; n < WN; ++n)
          acc[m][n] = __builtin_amdgcn_mfma_f32_16x16x32_bf16(af[m][ks], bfr[n][ks], acc[m][n], 0, 0, 0);
    __builtin_amdgcn_s_setprio(0);
    // counted wait: everything except A(u+2)'s 2 loads must have landed
    if (u + 2 < NT) asm volatile("s_waitcnt vmcnt(2)");
    else            asm volatile("s_waitcnt vmcnt(0)");
    __builtin_amdgcn_s_barrier();
  }
  // epilogue: D row=(lane>>4)*4+r, col=lane&15
#pragma unroll
  for (int m = 0; m < 4; ++m)
#pragma unroll
    for (int n = 0; n < WN; ++n)
#pragma unroll
      for (int r = 0; r < 4; ++r) {
        const int row = m0 + wm * 64 + m * 16 + laneh * 4 + r;
        const int col = n0 + wn * (WN * 16) + n * 16 + lane15;
        const float v = acc[m][n][r];
        if (OUT_BF16) ((u16*)Cout)[(size_t)row * N + col] = f2b(v);
        else          ((float*)Cout)[(size_t)row * N + col] = v;
      }
}

// ---------------- RoPE + rearrange: qkv -> Qr[h][t][d], Kr[g][t][d] ----------------
__global__ __launch_bounds__(256) void rope_rearrange(
    const u16* __restrict__ qkv, const float* __restrict__ cosT,
    const float* __restrict__ sinT, u16* __restrict__ Qr, u16* __restrict__ Kr) {
  const int u = blockIdx.x * 4 + (threadIdx.x >> 6);  // u = e*TT + t, e in [0,40)
  const int lane = threadIdx.x & 63;
  const int t = u & (TT - 1);
  const int e = u >> 11;
  const u16* in;
  u16* outp;
  if (e < NH) {
    in = qkv + (size_t)t * QKVN + e * HD;
    outp = Qr + ((size_t)e * TT + t) * HD;
  } else {
    const int g = e - NH;
    in = qkv + (size_t)t * QKVN + KOFF + g * HD;
    outp = Kr + ((size_t)g * TT + t) * HD;
  }
  const float u1 = b2f(in[lane]), u2 = b2f(in[lane + 64]);
  const float c1 = cosT[t * HD + lane], s1 = sinT[t * HD + lane];
  const float c2 = cosT[t * HD + lane + 64], s2 = sinT[t * HD + lane + 64];
  outp[lane]      = f2b(u1 * c1 - u2 * s1);   // d<64:  u*cos - u[d+64]*sin
  outp[lane + 64] = f2b(u2 * c2 + u1 * s2);   // d>=64: u*cos + u[d-64]*sin
}

// ---------------- V transpose per group: qkv V block -> VT[g][d][t] ----------------
__global__ __launch_bounds__(256) void vtrans(
    const u16* __restrict__ qkv, u16* __restrict__ VT) {
  __shared__ u16 tile[64][66];
  const int g = blockIdx.z;
  const int t0 = blockIdx.x * 64, d0 = blockIdx.y * 64;
  const int tid = threadIdx.x;
#pragma unroll
  for (int it = 0; it < 16; ++it) {
    int idx = it * 256 + tid;
    int i = idx >> 6, j = idx & 63;                       // i: t, j: d
    tile[i][j] = qkv[(size_t)(t0 + i) * QKVN + VOFF + g * HD + d0 + j];
  }
  __syncthreads();
#pragma unroll
  for (int it = 0; it < 16; ++it) {
    int idx = it * 256 + tid;
    int j = idx >> 6, i = idx & 63;
    VT[((size_t)g * HD + d0 + j) * TT + t0 + i] = tile[i][j];
  }
}

// ---------------- causal flash attention (GQA), balanced pairing + KV dbuf ----------------
// Block = (head h, pair p): q-tiles p and 15-p -> exactly 17 KV iterations/block.
// Grid = 256 (1/CU).  8 waves x 16 q-rows.  K/V double-buffered (counted vmcnt(8):
// next tile's loads stay in flight across the barrier); P in dedicated per-wave
// slab (no mid-iteration barrier).  LDS = 64+64+32 = 160 KB exactly.
__global__ __launch_bounds__(512) void attn(
    const u16* __restrict__ Qr, const u16* __restrict__ Kr,
    const u16* __restrict__ VT, u16* __restrict__ AO) {
  __shared__ __align__(16) u16 sK[2][128 * 128];   // [s][d] swizzled
  __shared__ __align__(16) u16 sV[2][128 * 128];   // [d][s] swizzled
  __shared__ __align__(16) u16 sP[8][16 * 128];    // per-wave P slab (private)
  // XCD-chunked bijective swizzle: 256 blocks = 8 XCDs x 32; chunk c = heads 4c..4c+3
  // = exactly KV group c -> each XCD's L2 sees one group's K/V (1MB).
  const int bid = blockIdx.x;
  const int swz = (bid & 7) * 32 + (bid >> 3);
  const int h = swz >> 3, p = swz & 7;
  const int g = h >> 2;
  const int tid = threadIdx.x, wid = tid >> 6, lane = tid & 63;
  const int lane15 = lane & 15, laneh = lane >> 4;
  const int xorL = (lane15 & 7) << 3;              // read-side swizzle (row = *+lane15)
  const u16* Qh = Qr + (size_t)h * TT * HD;
  const u16* Kg = Kr + (size_t)g * TT * HD;
  const u16* Vg = VT + (size_t)g * HD * TT;
  const float scale = 0.08838834764831845f;        // 1/sqrt(128)

  auto stageKV = [&](int buf, int kv) {            // 8 gloads/thread
#pragma unroll
    for (int i = 0; i < 4; ++i) {
      const int ebase = (wid * 4 + i) * 512;
      const int e = ebase + lane * 8;
      const int row = e >> 7;
      const int col = (e & 127) ^ ((row & 7) << 3);
      gload_lds16(Kg + (size_t)(kv * 128 + row) * HD + col, &sK[buf][ebase]);
      gload_lds16(Vg + (size_t)row * TT + kv * 128 + col, &sV[buf][ebase]);
    }
  };

  for (int pass = 0; pass < 2; ++pass) {
    const int qt = pass ? (15 - p) : p;
    // Q fragments for this q-tile: wave owns rows [qt*128 + wid*16, +16)
    bf16x8 qf[4];
    const int qrow0 = qt * 128 + wid * 16;
#pragma unroll
    for (int ks = 0; ks < 4; ++ks)
      qf[ks] = *(const bf16x8*)(Qh + (size_t)(qrow0 + lane15) * HD + ks * 32 + laneh * 8);

    f32x4 acc_o[8];
    float mrow[4], lrow[4];
#pragma unroll
    for (int n = 0; n < 8; ++n)
#pragma unroll
      for (int r = 0; r < 4; ++r) acc_o[n][r] = 0.f;
#pragma unroll
    for (int r = 0; r < 4; ++r) { mrow[r] = -1e30f; lrow[r] = 0.f; }

    stageKV(0, 0);
    for (int kv = 0; kv <= qt; ++kv) {
      const int cur = kv & 1;
      if (kv < qt) stageKV(cur ^ 1, kv + 1);       // buf^1 last read at kv-1 (barrier'd)
      __builtin_amdgcn_sched_barrier(0);
      if (kv < qt) asm volatile("s_waitcnt vmcnt(8)");   // drain stage(kv), keep kv+1 in flight
      else         asm volatile("s_waitcnt vmcnt(0)");
      __builtin_amdgcn_s_barrier();                // all waves' stage(kv) landed

      // S = Q K^T  (1 m-frag x 8 n-frags)
      f32x4 s[8];
#pragma unroll
      for (int n = 0; n < 8; ++n)
#pragma unroll
        for (int r = 0; r < 4; ++r) s[n][r] = 0.f;
      __builtin_amdgcn_s_setprio(1);
#pragma unroll
      for (int ks = 0; ks < 4; ++ks) {
        bf16x8 kf[8];
#pragma unroll
        for (int n = 0; n < 8; ++n)
          kf[n] = *(const bf16x8*)&sK[cur][(n * 16 + lane15) * 128 + ((ks * 32 + laneh * 8) ^ xorL)];
#pragma unroll
        for (int n = 0; n < 8; ++n)
          s[n] = __builtin_amdgcn_mfma_f32_16x16x32_bf16(qf[ks], kf[n], s[n], 0, 0, 0);
      }
      __builtin_amdgcn_s_setprio(0);

      // scale + causal mask (only diagonal tile needs the mask)
      if (kv == qt) {
#pragma unroll
        for (int n = 0; n < 8; ++n)
#pragma unroll
          for (int r = 0; r < 4; ++r) {
            const int ql = wid * 16 + laneh * 4 + r;
            const int sl = n * 16 + lane15;
            s[n][r] = (sl > ql) ? -1e30f : s[n][r] * scale;
          }
      } else {
#pragma unroll
        for (int n = 0; n < 8; ++n)
#pragma unroll
          for (int r = 0; r < 4; ++r) s[n][r] *= scale;
      }
      // online softmax: row lives in the 16 lanes sharing laneh; reduce via shfl_xor
#pragma unroll
      for (int r = 0; r < 4; ++r) {
        float pm = s[0][r];
#pragma unroll
        for (int n = 1; n < 8; ++n) pm = fmaxf(pm, s[n][r]);
        pm = fmaxf(pm, __shfl_xor(pm, 1));
        pm = fmaxf(pm, __shfl_xor(pm, 2));
        pm = fmaxf(pm, __shfl_xor(pm, 4));
        pm = fmaxf(pm, __shfl_xor(pm, 8));
        const float mnew = fmaxf(mrow[r], pm);
        const float corr = __expf(mrow[r] - mnew);
        mrow[r] = mnew;
        float ps = 0.f;
#pragma unroll
        for (int n = 0; n < 8; ++n) {
          const float pr = __expf(s[n][r] - mnew);
          s[n][r] = pr;
          ps += pr;
        }
        ps += __shfl_xor(ps, 1); ps += __shfl_xor(ps, 2);
        ps += __shfl_xor(ps, 4); ps += __shfl_xor(ps, 8);
        lrow[r] = lrow[r] * corr + ps;
#pragma unroll
        for (int n = 0; n < 8; ++n) acc_o[n][r] *= corr;
      }
      // P (D-frag layout) -> wave-private slab (swizzled write); no barrier needed
#pragma unroll
      for (int n = 0; n < 8; ++n)
#pragma unroll
        for (int r = 0; r < 4; ++r) {
          const int prow = laneh * 4 + r;
          const int pcol = (n * 16 + lane15) ^ ((prow & 7) << 3);
          sP[wid][prow * 128 + pcol] = f2b(s[n][r]);
        }
      // PV: O += P @ V   (pf from own slab; vf from sV; both swizzled reads)
      __builtin_amdgcn_s_setprio(1);
#pragma unroll
      for (int ks = 0; ks < 4; ++ks) {
        bf16x8 pf, vf[8];
        pf = *(const bf16x8*)&sP[wid][lane15 * 128 + ((ks * 32 + laneh * 8) ^ xorL)];
#pragma unroll
        for (int n = 0; n < 8; ++n)
          vf[n] = *(const bf16x8*)&sV[cur][(n * 16 + lane15) * 128 + ((ks * 32 + laneh * 8) ^ xorL)];
#pragma unroll
        for (int n = 0; n < 8; ++n)
          acc_o[n] = __builtin_amdgcn_mfma_f32_16x16x32_bf16(pf, vf[n], acc_o[n], 0, 0, 0);
      }
      __builtin_amdgcn_s_setprio(0);
      __builtin_amdgcn_s_barrier();   // reads of buf[cur] done before it is re-staged
    }
    // epilogue for this q-tile: AO[t][h*128+d] = O / l
    float inv[4];
#pragma unroll
    for (int r = 0; r < 4; ++r) inv[r] = 1.f / lrow[r];
#pragma unroll
    for (int n = 0; n < 8; ++n)
#pragma unroll
      for (int r = 0; r < 4; ++r) {
        const int trow = qt * 128 + wid * 16 + laneh * 4 + r;
        AO[(size_t)trow * DM + h * HD + n * 16 + lane15] = f2b(acc_o[n][r] * inv[r]);
      }
  }
}

// ---------------- launch ----------------
extern "C" void kernel_launch(void* const* d_in, const int* in_sizes, int n_in,
                              void* d_out, int out_size, void* d_ws, size_t ws_size,
                              hipStream_t stream) {
  const float* x     = (const float*)d_in[0];
  const float* w_qkv = (const float*)d_in[1];
  const float* w_out = (const float*)d_in[2];
  const float* cosT  = (const float*)d_in[3];
  const float* sinT  = (const float*)d_in[4];
  // d_in[5] (mask) unused: causal mask computed analytically
  float* out = (float*)d_out;

  char* ws = (char*)d_ws;
  // layout (bytes): wT region reused for wqT then woT (stream-ordered)
  u16* wT  = (u16*)(ws);                                   // 6144*4096 bf16 = 50331648 B
  u16* xb  = (u16*)(ws + 50331648);                        // 2048*4096 bf16 = 16777216 B (reused as AO)
  u16* qkv = (u16*)(ws + 50331648 + 16777216);             // 2048*6144 bf16 = 25165824 B
  u16* Qr  = (u16*)(ws + 50331648 + 16777216 + 25165824);  // 32*2048*128 bf16
  u16* Kr  = Qr + (size_t)NH * TT * HD;                    // 8*2048*128 bf16
  u16* VT  = Kr + (size_t)NG * TT * HD;                    // 8*128*2048 bf16
  u16* AO  = xb;                                           // alias: xb dead after GEMM1

  cvt_f32_bf16<<<2048, 256, 0, stream>>>(x, xb, TT * DM);
  transpose_cvt<<<dim3(QKVN / 64, DM / 64), 256, 0, stream>>>(w_qkv, wT, DM, QKVN);
  // GEMM1: BN=384 -> grid 16x16 = 256 blocks, exactly one dispatch wave
  gemm8p<6, true><<<dim3((TT / 128) * (QKVN / 384)), 512, 0, stream>>>(
      xb, wT, qkv, TT, QKVN, DM, QKVN / 384);
  rope_rearrange<<<(TT * (NH + NG)) / 4, 256, 0, stream>>>(qkv, cosT, sinT, Qr, Kr);
  vtrans<<<dim3(TT / 64, HD / 64, NG), 256, 0, stream>>>(qkv, VT);
  transpose_cvt<<<dim3(DM / 64, DM / 64), 256, 0, stream>>>(w_out, wT, DM, DM);  // after GEMM1: safe reuse
  attn<<<NH * 8, 512, 0, stream>>>(Qr, Kr, VT, AO);
  // GEMM2: BN=256 -> grid 16x16 = 256 blocks
  gemm8p<4, false><<<dim3((TT / 128) * (DM / 256)), 512, 0, stream>>>(
      AO, wT, out, TT, DM, DM, DM / 256);
}

// Round 6
// 317.464 us; speedup vs baseline: 1.7951x; 1.0378x over previous
//
#include <hip/hip_runtime.h>
#include <cstdint>
#include <cstddef>

// Problem constants
#define TT   2048   // tokens
#define DM   4096   // d_model
#define NH   32     // q heads
#define NG   8      // kv groups
#define HD   128    // head dim
#define QKVN 6144   // (32+16)*128
#define KOFF 4096   // k column offset in qkv
#define VOFF 5120   // v column offset in qkv

typedef __attribute__((ext_vector_type(8))) short bf16x8;   // 8 bf16 (4 VGPRs)
typedef __attribute__((ext_vector_type(4))) float f32x4;    // MFMA 16x16 accumulator
typedef unsigned short u16;

__device__ __forceinline__ u16 f2b(float f) {   // f32 -> bf16 RNE
  unsigned u = __builtin_bit_cast(unsigned, f);
  u += 0x7fffu + ((u >> 16) & 1u);
  return (u16)(u >> 16);
}
__device__ __forceinline__ float b2f(u16 s) {
  unsigned u = ((unsigned)s) << 16;
  return __builtin_bit_cast(float, u);
}

// async global->LDS, 16B per lane; LDS dest = wave-uniform base + lane*16
__device__ __forceinline__ void gload_lds16(const void* g, void* l) {
  __builtin_amdgcn_global_load_lds(
      (const __attribute__((address_space(1))) unsigned int*)g,
      (__attribute__((address_space(3))) unsigned int*)l,
      16, 0, 0);
}

// ---------------- elementwise f32 -> bf16 ----------------
__global__ __launch_bounds__(256) void cvt_f32_bf16(
    const float* __restrict__ src, u16* __restrict__ dst, int n) {
  for (int i = (blockIdx.x * 256 + threadIdx.x) * 4; i < n; i += gridDim.x * 256 * 4) {
    float4 v = *(const float4*)(src + i);
    ushort4 o;
    o.x = f2b(v.x); o.y = f2b(v.y); o.z = f2b(v.z); o.w = f2b(v.w);
    *(ushort4*)(dst + i) = o;
  }
}

// ---------------- transpose + convert: src f32 [R][C] -> dst bf16 [C][R] ----------------
// vectorized: float4 loads, transposed LDS scatter (stride 68 u16: 8B-aligned rows,
// banks spread), ushort4 stores (contiguous along R).
__global__ __launch_bounds__(256) void transpose_cvt(
    const float* __restrict__ src, u16* __restrict__ dst, int R, int C) {
  __shared__ __align__(16) u16 tile[64 * 68];
  const int rb = blockIdx.y * 64, cb = blockIdx.x * 64;
  const int tid = threadIdx.x;
#pragma unroll
  for (int it = 0; it < 4; ++it) {
    const int idx = it * 256 + tid;            // [0,1024)
    const int r = idx >> 4, c4 = (idx & 15) * 4;
    const float4 v = *(const float4*)(src + (size_t)(rb + r) * C + cb + c4);
    tile[(c4 + 0) * 68 + r] = f2b(v.x);
    tile[(c4 + 1) * 68 + r] = f2b(v.y);
    tile[(c4 + 2) * 68 + r] = f2b(v.z);
    tile[(c4 + 3) * 68 + r] = f2b(v.w);
  }
  __syncthreads();
#pragma unroll
  for (int it = 0; it < 4; ++it) {
    const int idx = it * 256 + tid;
    const int c = idx >> 4, r4 = (idx & 15) * 4;
    const ushort4 o = *(const ushort4*)&tile[c * 68 + r4];
    *(ushort4*)(dst + (size_t)(cb + c) * R + rb + r4) = o;
  }
}

// ---------------- bf16 GEMM, phase-split counted-vmcnt template ----------------
// C[M][N] = A[M][K] * Bt[N][K]^T.  BM=128, BN=WN*64, BK=64, 512 thr = 8 waves
// (2Mx4N), per-wave 64 x WN*16 (acc 4xWN).  2 phases / K-tile, only TWO barriers
// per K-tile: (B1) between phase0 (reads of sA[cur]) and phase1's stageA overwrite
// of sA[cur]; (B2) end-of-iteration staging fence after the counted vmcnt(2).
// A wave reaching a barrier has retired its ds_reads (its MFMAs consumed them),
// so no explicit lgkm drain is needed -> waves skew across phases and ds_read
// overlaps MFMA cross-wave.  LDS XOR-swizzled col ^= ((row&7)<<3) via
// pre-swizzled global source (rule #21).
template <int WN, bool OUT_BF16>
__global__ __launch_bounds__(512) void gemm8p(
    const u16* __restrict__ A, const u16* __restrict__ Bt, void* __restrict__ Cout,
    int M, int N, int K, int nbx) {
  __shared__ __align__(16) u16 sA[2][128 * 64];
  __shared__ __align__(16) u16 sB[2][WN * 64 * 64];
  const int tid = threadIdx.x;
  const int wid = tid >> 6, lane = tid & 63;
  const int lane15 = lane & 15, laneh = lane >> 4;
  const int wm = wid >> 2, wn = wid & 3;
  // bijective XCD swizzle (grid % 8 == 0); chunk shares A row-panels for L2
  const int cpx = gridDim.x >> 3;
  const int swz = ((int)blockIdx.x & 7) * cpx + ((int)blockIdx.x >> 3);
  const int m0 = (swz / nbx) * 128, n0 = (swz % nbx) * (WN * 64);
  const int xorL = (lane15 & 7) << 3;

  f32x4 acc[4][WN];
#pragma unroll
  for (int m = 0; m < 4; ++m)
#pragma unroll
    for (int n = 0; n < WN; ++n)
#pragma unroll
      for (int r = 0; r < 4; ++r) acc[m][n][r] = 0.f;

  auto stageA = [&](int buf, int t) {
    const int k0 = t << 6;
#pragma unroll
    for (int i = 0; i < 2; ++i) {
      const int ebase = (wid * 2 + i) * 512;
      const int e = ebase + lane * 8;
      const int row = e >> 6;
      const int col = (e & 63) ^ ((row & 7) << 3);
      gload_lds16(A + (size_t)(m0 + row) * K + k0 + col, &sA[buf][ebase]);
    }
  };
  auto stageB = [&](int buf, int t) {
    const int k0 = t << 6;
#pragma unroll
    for (int i = 0; i < WN; ++i) {
      const int ebase = (wid * WN + i) * 512;
      const int e = ebase + lane * 8;
      const int row = e >> 6;
      const int col = (e & 63) ^ ((row & 7) << 3);
      gload_lds16(Bt + (size_t)(n0 + row) * K + k0 + col, &sB[buf][ebase]);
    }
  };

  const int NT = K >> 6;
  // prologue: A(0), B(0), A(1) in flight; need A0+B0 landed -> vmcnt(2)
  stageA(0, 0);
  stageB(0, 0);
  stageA(1, 1);
  asm volatile("s_waitcnt vmcnt(2)");
  __builtin_amdgcn_s_barrier();

  for (int u = 0; u < NT; ++u) {
    const int cur = u & 1;
    bf16x8 af[4][2], bfr[WN][2];
    // ==== phase 0: read af(all) + bfr(first half); stage B(u+1); MFMA half 0 ====
#pragma unroll
    for (int m = 0; m < 4; ++m)
#pragma unroll
      for (int ks = 0; ks < 2; ++ks)
        af[m][ks] = *(const bf16x8*)&sA[cur][(wm * 64 + m * 16 + lane15) * 64 +
                                            ((ks * 32 + laneh * 8) ^ xorL)];
#pragma unroll
    for (int n = 0; n < WN / 2; ++n)
#pragma unroll
      for (int ks = 0; ks < 2; ++ks)
        bfr[n][ks] = *(const bf16x8*)&sB[cur][(wn * (WN * 16) + n * 16 + lane15) * 64 +
                                             ((ks * 32 + laneh * 8) ^ xorL)];
    if (u + 1 < NT) stageB(cur ^ 1, u + 1);   // overwrites B(u-1): readers drained at prev B2
    __builtin_amdgcn_sched_barrier(0);
    __builtin_amdgcn_s_setprio(1);
#pragma unroll
    for (int ks = 0; ks < 2; ++ks)
#pragma unroll
      for (int m = 0; m < 4; ++m)
#pragma unroll
        for (int n = 0; n < WN / 2; ++n)
          acc[m][n] = __builtin_amdgcn_mfma_f32_16x16x32_bf16(af[m][ks], bfr[n][ks], acc[m][n], 0, 0, 0);
    __builtin_amdgcn_s_setprio(0);
    __builtin_amdgcn_s_barrier();             // B1: all waves' sA[cur] reads retired
    // ==== phase 1: read bfr(second half); stage A(u+2); MFMA half 1; vmcnt; B2 ====
#pragma unroll
    for (int n = WN / 2; n < WN; ++n)
#pragma unroll
      for (int ks = 0; ks < 2; ++ks)
        bfr[n][ks] = *(const bf16x8*)&sB[cur][(wn * (WN * 16) + n * 16 + lane15) * 64 +
                                             ((ks * 32 + laneh * 8) ^ xorL)];
    if (u + 2 < NT) stageA(cur, u + 2);       // overwrites A(u): safe after B1
    __builtin_amdgcn_sched_barrier(0);
    __builtin_amdgcn_s_setprio(1);
#pragma unroll
    for (int ks = 0; ks < 2; ++ks)
#pragma unroll
      for (int m = 0; m < 4; ++m)
#pragma unroll
        for (int n = WN / 2; n < WN; ++n)
          acc[m][n] = __builtin_amdgcn_mfma_f32_16x16x32_bf16(af[m][ks], bfr[n][ks], acc[m][n], 0, 0, 0);
    __builtin_amdgcn_s_setprio(0);
    // counted wait: everything except A(u+2)'s 2 loads must have landed
    if (u + 2 < NT) asm volatile("s_waitcnt vmcnt(2)");
    else            asm volatile("s_waitcnt vmcnt(0)");
    __builtin_amdgcn_s_barrier();             // B2: staging fence for next iteration
  }
  // epilogue: D row=(lane>>4)*4+r, col=lane&15
#pragma unroll
  for (int m = 0; m < 4; ++m)
#pragma unroll
    for (int n = 0; n < WN; ++n)
#pragma unroll
      for (int r = 0; r < 4; ++r) {
        const int row = m0 + wm * 64 + m * 16 + laneh * 4 + r;
        const int col = n0 + wn * (WN * 16) + n * 16 + lane15;
        const float v = acc[m][n][r];
        if (OUT_BF16) ((u16*)Cout)[(size_t)row * N + col] = f2b(v);
        else          ((float*)Cout)[(size_t)row * N + col] = v;
      }
}

// ---------------- RoPE + rearrange: qkv -> Qr[h][t][d], Kr[g][t][d] ----------------
__global__ __launch_bounds__(256) void rope_rearrange(
    const u16* __restrict__ qkv, const float* __restrict__ cosT,
    const float* __restrict__ sinT, u16* __restrict__ Qr, u16* __restrict__ Kr) {
  const int u = blockIdx.x * 4 + (threadIdx.x >> 6);  // u = e*TT + t, e in [0,40)
  const int lane = threadIdx.x & 63;
  const int t = u & (TT - 1);
  const int e = u >> 11;
  const u16* in;
  u16* outp;
  if (e < NH) {
    in = qkv + (size_t)t * QKVN + e * HD;
    outp = Qr + ((size_t)e * TT + t) * HD;
  } else {
    const int g = e - NH;
    in = qkv + (size_t)t * QKVN + KOFF + g * HD;
    outp = Kr + ((size_t)g * TT + t) * HD;
  }
  const float u1 = b2f(in[lane]), u2 = b2f(in[lane + 64]);
  const float c1 = cosT[t * HD + lane], s1 = sinT[t * HD + lane];
  const float c2 = cosT[t * HD + lane + 64], s2 = sinT[t * HD + lane + 64];
  outp[lane]      = f2b(u1 * c1 - u2 * s1);   // d<64:  u*cos - u[d+64]*sin
  outp[lane + 64] = f2b(u2 * c2 + u1 * s2);   // d>=64: u*cos + u[d-64]*sin
}

// ---------------- V transpose per group: qkv V block -> VT[g][d][t] ----------------
__global__ __launch_bounds__(256) void vtrans(
    const u16* __restrict__ qkv, u16* __restrict__ VT) {
  __shared__ u16 tile[64][66];
  const int g = blockIdx.z;
  const int t0 = blockIdx.x * 64, d0 = blockIdx.y * 64;
  const int tid = threadIdx.x;
#pragma unroll
  for (int it = 0; it < 16; ++it) {
    int idx = it * 256 + tid;
    int i = idx >> 6, j = idx & 63;                       // i: t, j: d
    tile[i][j] = qkv[(size_t)(t0 + i) * QKVN + VOFF + g * HD + d0 + j];
  }
  __syncthreads();
#pragma unroll
  for (int it = 0; it < 16; ++it) {
    int idx = it * 256 + tid;
    int j = idx >> 6, i = idx & 63;
    VT[((size_t)g * HD + d0 + j) * TT + t0 + i] = tile[i][j];
  }
}

// ---------------- causal flash attention (GQA), balanced pairing + KV dbuf ----------------
// Block = (head h, pair p): q-tiles p and 15-p -> exactly 17 KV iterations/block.
// Grid = 256 (1/CU).  8 waves x 16 q-rows.  K/V double-buffered (counted vmcnt(8):
// next tile's loads stay in flight across the barrier); P in dedicated per-wave
// slab (no mid-iteration barrier).  LDS = 64+64+32 = 160 KB exactly.
__global__ __launch_bounds__(512) void attn(
    const u16* __restrict__ Qr, const u16* __restrict__ Kr,
    const u16* __restrict__ VT, u16* __restrict__ AO) {
  __shared__ __align__(16) u16 sK[2][128 * 128];   // [s][d] swizzled
  __shared__ __align__(16) u16 sV[2][128 * 128];   // [d][s] swizzled
  __shared__ __align__(16) u16 sP[8][16 * 128];    // per-wave P slab (private)
  // XCD-chunked bijective swizzle: 256 blocks = 8 XCDs x 32; chunk c = heads 4c..4c+3
  // = exactly KV group c -> each XCD's L2 sees one group's K/V (1MB).
  const int bid = blockIdx.x;
  const int swz = (bid & 7) * 32 + (bid >> 3);
  const int h = swz >> 3, p = swz & 7;
  const int g = h >> 2;
  const int tid = threadIdx.x, wid = tid >> 6, lane = tid & 63;
  const int lane15 = lane & 15, laneh = lane >> 4;
  const int xorL = (lane15 & 7) << 3;              // read-side swizzle (row = *+lane15)
  const u16* Qh = Qr + (size_t)h * TT * HD;
  const u16* Kg = Kr + (size_t)g * TT * HD;
  const u16* Vg = VT + (size_t)g * HD * TT;
  const float scale = 0.08838834764831845f;        // 1/sqrt(128)

  auto stageKV = [&](int buf, int kv) {            // 8 gloads/thread
#pragma unroll
    for (int i = 0; i < 4; ++i) {
      const int ebase = (wid * 4 + i) * 512;
      const int e = ebase + lane * 8;
      const int row = e >> 7;
      const int col = (e & 127) ^ ((row & 7) << 3);
      gload_lds16(Kg + (size_t)(kv * 128 + row) * HD + col, &sK[buf][ebase]);
      gload_lds16(Vg + (size_t)row * TT + kv * 128 + col, &sV[buf][ebase]);
    }
  };

  for (int pass = 0; pass < 2; ++pass) {
    const int qt = pass ? (15 - p) : p;
    // Q fragments for this q-tile: wave owns rows [qt*128 + wid*16, +16)
    bf16x8 qf[4];
    const int qrow0 = qt * 128 + wid * 16;
#pragma unroll
    for (int ks = 0; ks < 4; ++ks)
      qf[ks] = *(const bf16x8*)(Qh + (size_t)(qrow0 + lane15) * HD + ks * 32 + laneh * 8);

    f32x4 acc_o[8];
    float mrow[4], lrow[4];
#pragma unroll
    for (int n = 0; n < 8; ++n)
#pragma unroll
      for (int r = 0; r < 4; ++r) acc_o[n][r] = 0.f;
#pragma unroll
    for (int r = 0; r < 4; ++r) { mrow[r] = -1e30f; lrow[r] = 0.f; }

    stageKV(0, 0);
    for (int kv = 0; kv <= qt; ++kv) {
      const int cur = kv & 1;
      if (kv < qt) stageKV(cur ^ 1, kv + 1);       // buf^1 last read at kv-1 (barrier'd)
      __builtin_amdgcn_sched_barrier(0);
      if (kv < qt) asm volatile("s_waitcnt vmcnt(8)");   // drain stage(kv), keep kv+1 in flight
      else         asm volatile("s_waitcnt vmcnt(0)");
      __builtin_amdgcn_s_barrier();                // all waves' stage(kv) landed

      // S = Q K^T  (1 m-frag x 8 n-frags)
      f32x4 s[8];
#pragma unroll
      for (int n = 0; n < 8; ++n)
#pragma unroll
        for (int r = 0; r < 4; ++r) s[n][r] = 0.f;
      __builtin_amdgcn_s_setprio(1);
#pragma unroll
      for (int ks = 0; ks < 4; ++ks) {
        bf16x8 kf[8];
#pragma unroll
        for (int n = 0; n < 8; ++n)
          kf[n] = *(const bf16x8*)&sK[cur][(n * 16 + lane15) * 128 + ((ks * 32 + laneh * 8) ^ xorL)];
#pragma unroll
        for (int n = 0; n < 8; ++n)
          s[n] = __builtin_amdgcn_mfma_f32_16x16x32_bf16(qf[ks], kf[n], s[n], 0, 0, 0);
      }
      __builtin_amdgcn_s_setprio(0);

      // scale + causal mask (only diagonal tile needs the mask)
      if (kv == qt) {
#pragma unroll
        for (int n = 0; n < 8; ++n)
#pragma unroll
          for (int r = 0; r < 4; ++r) {
            const int ql = wid * 16 + laneh * 4 + r;
            const int sl = n * 16 + lane15;
            s[n][r] = (sl > ql) ? -1e30f : s[n][r] * scale;
          }
      } else {
#pragma unroll
        for (int n = 0; n < 8; ++n)
#pragma unroll
          for (int r = 0; r < 4; ++r) s[n][r] *= scale;
      }
      // online softmax: row lives in the 16 lanes sharing laneh; reduce via shfl_xor
#pragma unroll
      for (int r = 0; r < 4; ++r) {
        float pm = s[0][r];
#pragma unroll
        for (int n = 1; n < 8; ++n) pm = fmaxf(pm, s[n][r]);
        pm = fmaxf(pm, __shfl_xor(pm, 1));
        pm = fmaxf(pm, __shfl_xor(pm, 2));
        pm = fmaxf(pm, __shfl_xor(pm, 4));
        pm = fmaxf(pm, __shfl_xor(pm, 8));
        const float mnew = fmaxf(mrow[r], pm);
        const float corr = __expf(mrow[r] - mnew);
        mrow[r] = mnew;
        float ps = 0.f;
#pragma unroll
        for (int n = 0; n < 8; ++n) {
          const float pr = __expf(s[n][r] - mnew);
          s[n][r] = pr;
          ps += pr;
        }
        ps += __shfl_xor(ps, 1); ps += __shfl_xor(ps, 2);
        ps += __shfl_xor(ps, 4); ps += __shfl_xor(ps, 8);
        lrow[r] = lrow[r] * corr + ps;
#pragma unroll
        for (int n = 0; n < 8; ++n) acc_o[n][r] *= corr;
      }
      // P (D-frag layout) -> wave-private slab (swizzled write); no barrier needed
#pragma unroll
      for (int n = 0; n < 8; ++n)
#pragma unroll
        for (int r = 0; r < 4; ++r) {
          const int prow = laneh * 4 + r;
          const int pcol = (n * 16 + lane15) ^ ((prow & 7) << 3);
          sP[wid][prow * 128 + pcol] = f2b(s[n][r]);
        }
      // PV: O += P @ V   (pf from own slab; vf from sV; both swizzled reads)
      __builtin_amdgcn_s_setprio(1);
#pragma unroll
      for (int ks = 0; ks < 4; ++ks) {
        bf16x8 pf, vf[8];
        pf = *(const bf16x8*)&sP[wid][lane15 * 128 + ((ks * 32 + laneh * 8) ^ xorL)];
#pragma unroll
        for (int n = 0; n < 8; ++n)
          vf[n] = *(const bf16x8*)&sV[cur][(n * 16 + lane15) * 128 + ((ks * 32 + laneh * 8) ^ xorL)];
#pragma unroll
        for (int n = 0; n < 8; ++n)
          acc_o[n] = __builtin_amdgcn_mfma_f32_16x16x32_bf16(pf, vf[n], acc_o[n], 0, 0, 0);
      }
      __builtin_amdgcn_s_setprio(0);
      __builtin_amdgcn_s_barrier();   // reads of buf[cur] done before it is re-staged
    }
    // epilogue for this q-tile: AO[t][h*128+d] = O / l
    float inv[4];
#pragma unroll
    for (int r = 0; r < 4; ++r) inv[r] = 1.f / lrow[r];
#pragma unroll
    for (int n = 0; n < 8; ++n)
#pragma unroll
      for (int r = 0; r < 4; ++r) {
        const int trow = qt * 128 + wid * 16 + laneh * 4 + r;
        AO[(size_t)trow * DM + h * HD + n * 16 + lane15] = f2b(acc_o[n][r] * inv[r]);
      }
  }
}

// ---------------- launch ----------------
extern "C" void kernel_launch(void* const* d_in, const int* in_sizes, int n_in,
                              void* d_out, int out_size, void* d_ws, size_t ws_size,
                              hipStream_t stream) {
  const float* x     = (const float*)d_in[0];
  const float* w_qkv = (const float*)d_in[1];
  const float* w_out = (const float*)d_in[2];
  const float* cosT  = (const float*)d_in[3];
  const float* sinT  = (const float*)d_in[4];
  // d_in[5] (mask) unused: causal mask computed analytically
  float* out = (float*)d_out;

  char* ws = (char*)d_ws;
  // layout (bytes): wT region reused for wqT then woT (stream-ordered)
  u16* wT  = (u16*)(ws);                                   // 6144*4096 bf16 = 50331648 B
  u16* xb  = (u16*)(ws + 50331648);                        // 2048*4096 bf16 = 16777216 B (reused as AO)
  u16* qkv = (u16*)(ws + 50331648 + 16777216);             // 2048*6144 bf16 = 25165824 B
  u16* Qr  = (u16*)(ws + 50331648 + 16777216 + 25165824);  // 32*2048*128 bf16
  u16* Kr  = Qr + (size_t)NH * TT * HD;                    // 8*2048*128 bf16
  u16* VT  = Kr + (size_t)NG * TT * HD;                    // 8*128*2048 bf16
  u16* AO  = xb;                                           // alias: xb dead after GEMM1

  cvt_f32_bf16<<<2048, 256, 0, stream>>>(x, xb, TT * DM);
  transpose_cvt<<<dim3(QKVN / 64, DM / 64), 256, 0, stream>>>(w_qkv, wT, DM, QKVN);
  // GEMM1: BN=384 -> grid 16x16 = 256 blocks, exactly one dispatch wave
  gemm8p<6, true><<<dim3((TT / 128) * (QKVN / 384)), 512, 0, stream>>>(
      xb, wT, qkv, TT, QKVN, DM, QKVN / 384);
  rope_rearrange<<<(TT * (NH + NG)) / 4, 256, 0, stream>>>(qkv, cosT, sinT, Qr, Kr);
  vtrans<<<dim3(TT / 64, HD / 64, NG), 256, 0, stream>>>(qkv, VT);
  transpose_cvt<<<dim3(DM / 64, DM / 64), 256, 0, stream>>>(w_out, wT, DM, DM);  // after GEMM1: safe reuse
  attn<<<NH * 8, 512, 0, stream>>>(Qr, Kr, VT, AO);
  // GEMM2: BN=256 -> grid 16x16 = 256 blocks
  gemm8p<4, false><<<dim3((TT / 128) * (DM / 256)), 512, 0, stream>>>(
      AO, wT, out, TT, DM, DM, DM / 256);
}